// Round 3
// baseline (1620.167 us; speedup 1.0000x reference)
//
#include <hip/hip_runtime.h>

typedef __attribute__((ext_vector_type(8))) short bf16x8;
typedef __attribute__((ext_vector_type(4))) float f32x4;

// ---------------- CSR build ----------------

__global__ void hist_kernel(const int* __restrict__ dst, int E, int* __restrict__ deg){
    int e = blockIdx.x*256 + threadIdx.x;
    if(e < E) atomicAdd(&deg[dst[e]], 1);
}

__global__ void scan_part(const int* __restrict__ deg, int n, int* __restrict__ partials){
    __shared__ int sm[256];
    int t = threadIdx.x;
    int idx = blockIdx.x*256 + t;
    sm[t] = (idx < n) ? deg[idx] : 0;
    __syncthreads();
    for(int s = 128; s > 0; s >>= 1){ if(t < s) sm[t] += sm[t+s]; __syncthreads(); }
    if(t == 0) partials[blockIdx.x] = sm[0];
}

__global__ void scan_partials_k(int* __restrict__ partials, int nb){
    __shared__ int sm[512];
    int t = threadIdx.x;
    int orig = (t < nb) ? partials[t] : 0;
    sm[t] = orig; __syncthreads();
    for(int s = 1; s < 512; s <<= 1){
        int add = (t >= s) ? sm[t-s] : 0;
        __syncthreads();
        sm[t] += add;
        __syncthreads();
    }
    if(t < nb) partials[t] = sm[t] - orig;   // exclusive
}

__global__ void scan_final(const int* __restrict__ deg, int n,
                           const int* __restrict__ partials, int* __restrict__ row_start,
                           float* __restrict__ dinv){
    __shared__ int sm[256];
    int t = threadIdx.x;
    int idx = blockIdx.x*256 + t;
    int orig = (idx < n) ? deg[idx] : 0;
    sm[t] = orig; __syncthreads();
    for(int s = 1; s < 256; s <<= 1){
        int add = (t >= s) ? sm[t-s] : 0;
        __syncthreads();
        sm[t] += add;
        __syncthreads();
    }
    int excl = partials[blockIdx.x] + sm[t] - orig;
    if(idx < n){
        row_start[idx] = excl;
        dinv[idx] = rsqrtf((float)orig + 1.0f);
    }
    if(idx == n-1) row_start[n] = excl + orig;   // == E
}

__global__ void fill_csr(const int* __restrict__ src, const int* __restrict__ dst, int E,
                         const int* __restrict__ row_start, int* __restrict__ cursor,
                         int* __restrict__ csr_src){
    int e = blockIdx.x*256 + threadIdx.x;
    if(e < E){
        int d = dst[e];
        int p = atomicAdd(&cursor[d], 1);
        csr_src[row_start[d] + p] = src[e];
    }
}

// ---------------- weight prep: f32 -> transposed bf16 hi/lo ----------------
// m=0..2: square layers -> [col][128] at m*16384
// m=3..5: JK blocks     -> [col][384] at 3*16384 (col stride 384, k = (m-3)*128 + klocal)

__device__ inline void split_bf16(float x, unsigned short& h, unsigned short& l){
    union { float f; unsigned int u; } cv;
    cv.f = x;
    unsigned int u = cv.u;
    unsigned int rh = u + 0x7fffu + ((u >> 16) & 1u);
    h = (unsigned short)(rh >> 16);
    union { unsigned int u; float f; } hb;
    hb.u = ((unsigned int)h) << 16;
    float r = x - hb.f;
    cv.f = r;
    unsigned int u2 = cv.u;
    unsigned int rl = u2 + 0x7fffu + ((u2 >> 16) & 1u);
    l = (unsigned short)(rl >> 16);
}

__global__ void prep_w_all(const float* __restrict__ W0, const float* __restrict__ W1,
                           const float* __restrict__ W2, const float* __restrict__ Wjk,
                           unsigned short* __restrict__ hi, unsigned short* __restrict__ lo){
    int m = blockIdx.x >> 6;                         // 0..5
    int i = (blockIdx.x & 63)*256 + threadIdx.x;     // 0..16383
    const float* W = (m==0) ? W0 : (m==1) ? W1 : (m==2) ? W2 : (Wjk + (m-3)*16384);
    int k = i >> 7, c = i & 127;
    unsigned short h, l;
    split_bf16(W[i], h, l);
    size_t o = (m < 3) ? ((size_t)m*16384 + c*128 + k)
                       : ((size_t)3*16384 + c*384 + (m-3)*128 + k);
    hi[o] = h;
    lo[o] = l;
}

// ---------------- MFMA GEMM: out[n,128] = in[n,128] @ W (*dinv_row) ----------------
// Slice-major (SM) layout: elem(node,k) at ((k>>3)*n + node)*8 + (k&7).
// A frag (16x16x32): lane holds A[lane&15][(lane>>4)*8 + j]; C/D: col=lane&15, row=(lane>>4)*4+reg.

template<bool ASM, bool OSM, bool SCALE>
__global__ __launch_bounds__(256) void gemm_mfma(const float* __restrict__ in,
                                                 const unsigned short* __restrict__ Wt_hi,
                                                 const unsigned short* __restrict__ Wt_lo,
                                                 const float* __restrict__ dinv,
                                                 float* __restrict__ out, int n){
    int t = threadIdx.x;
    int wave = t >> 6, lane = t & 63;
    int r0 = blockIdx.x*64 + wave*16;
    if(r0 >= n) return;
    int lr = lane & 15;
    int lk = (lane >> 4) * 8;

    f32x4 acc[8];
    #pragma unroll
    for(int c = 0; c < 8; ++c) acc[c] = (f32x4){0.f, 0.f, 0.f, 0.f};

    int row = r0 + lr;
    const unsigned short* bh = Wt_hi + lr*128 + lk;
    const unsigned short* bl = Wt_lo + lr*128 + lk;

    #pragma unroll
    for(int k0 = 0; k0 < 128; k0 += 32){
        int kb = k0 + lk;                      // multiple of 8
        const float* ap = ASM ? (in + ((size_t)(kb >> 3)*n + row)*8)
                              : (in + (size_t)row*128 + kb);
        f32x4 a0 = *(const f32x4*)ap;
        f32x4 a1 = *(const f32x4*)(ap + 4);
        bf16x8 ahi, alo;
        #pragma unroll
        for(int j = 0; j < 4; ++j){
            unsigned short h, l;
            split_bf16(a0[j], h, l);
            ahi[j] = (short)h; alo[j] = (short)l;
            split_bf16(a1[j], h, l);
            ahi[j+4] = (short)h; alo[j+4] = (short)l;
        }
        #pragma unroll
        for(int c = 0; c < 8; ++c){
            bf16x8 bhi = *(const bf16x8*)(bh + c*2048 + k0);
            bf16x8 blo = *(const bf16x8*)(bl + c*2048 + k0);
            acc[c] = __builtin_amdgcn_mfma_f32_16x16x32_bf16(ahi, bhi, acc[c], 0, 0, 0);
            acc[c] = __builtin_amdgcn_mfma_f32_16x16x32_bf16(alo, bhi, acc[c], 0, 0, 0);
            acc[c] = __builtin_amdgcn_mfma_f32_16x16x32_bf16(ahi, blo, acc[c], 0, 0, 0);
        }
    }

    float dv[4];
    #pragma unroll
    for(int i = 0; i < 4; ++i){
        int crow = r0 + ((lane >> 4) << 2) + i;
        dv[i] = SCALE ? dinv[crow] : 1.f;
    }
    #pragma unroll
    for(int c = 0; c < 8; ++c){
        int ccol = c*16 + lr;
        #pragma unroll
        for(int i = 0; i < 4; ++i){
            int crow = r0 + ((lane >> 4) << 2) + i;
            float v = acc[c][i];
            if(SCALE) v *= dv[i];
            if(OSM) out[((size_t)(ccol >> 3)*n + crow)*8 + (ccol & 7)] = v;
            else    out[(size_t)crow*128 + ccol] = v;
        }
    }
}

// ---------------- JK GEMM: out[n,128] = [A1|A2|A3][n,384] @ Wjk + bjk (SM inputs, RM output) ----------------

__global__ __launch_bounds__(256) void gemm_jk(const float* __restrict__ habc,
                                               const unsigned short* __restrict__ Wt_hi,
                                               const unsigned short* __restrict__ Wt_lo,
                                               const float* __restrict__ bias,
                                               float* __restrict__ out, int n){
    int t = threadIdx.x;
    int wave = t >> 6, lane = t & 63;
    int r0 = blockIdx.x*64 + wave*16;
    if(r0 >= n) return;
    int lr = lane & 15;
    int lk = (lane >> 4) * 8;

    f32x4 acc[8];
    #pragma unroll
    for(int c = 0; c < 8; ++c) acc[c] = (f32x4){0.f, 0.f, 0.f, 0.f};

    int row = r0 + lr;
    const unsigned short* bh = Wt_hi + lr*384 + lk;
    const unsigned short* bl = Wt_lo + lr*384 + lk;

    #pragma unroll
    for(int kb3 = 0; kb3 < 3; ++kb3){
        const float* in = habc + (size_t)kb3*n*128;
        #pragma unroll
        for(int k0 = 0; k0 < 128; k0 += 32){
            int kb = k0 + lk;
            const float* ap = in + ((size_t)(kb >> 3)*n + row)*8;
            f32x4 a0 = *(const f32x4*)ap;
            f32x4 a1 = *(const f32x4*)(ap + 4);
            bf16x8 ahi, alo;
            #pragma unroll
            for(int j = 0; j < 4; ++j){
                unsigned short h, l;
                split_bf16(a0[j], h, l);
                ahi[j] = (short)h; alo[j] = (short)l;
                split_bf16(a1[j], h, l);
                ahi[j+4] = (short)h; alo[j+4] = (short)l;
            }
            int ko = kb3*128 + k0;
            #pragma unroll
            for(int c = 0; c < 8; ++c){
                bf16x8 bhi = *(const bf16x8*)(bh + c*6144 + ko);
                bf16x8 blo = *(const bf16x8*)(bl + c*6144 + ko);
                acc[c] = __builtin_amdgcn_mfma_f32_16x16x32_bf16(ahi, bhi, acc[c], 0, 0, 0);
                acc[c] = __builtin_amdgcn_mfma_f32_16x16x32_bf16(alo, bhi, acc[c], 0, 0, 0);
                acc[c] = __builtin_amdgcn_mfma_f32_16x16x32_bf16(ahi, blo, acc[c], 0, 0, 0);
            }
        }
    }

    #pragma unroll
    for(int c = 0; c < 8; ++c){
        int ccol = c*16 + lr;
        float bcol = bias[ccol];
        #pragma unroll
        for(int i = 0; i < 4; ++i){
            int crow = r0 + ((lane >> 4) << 2) + i;
            out[(size_t)crow*128 + ccol] = acc[c][i] + bcol;
        }
    }
}

// ---------------- feature-sliced pull aggregation (SM layout) ----------------
// out_sm[node] = relu(dinv[node]*(y_sm[node] + sum_src y_sm[src]) + b), 8 features per slice.
// blockIdx.y = slice (slow dispatch dim -> phase-aligned, slice of Y is 3.2MB -> L2-resident per XCD).

__global__ __launch_bounds__(256) void aggregate_sm(const float* __restrict__ y, const int* __restrict__ row_start,
                                                    const int* __restrict__ csr, const float* __restrict__ dinv,
                                                    const float* __restrict__ bias, float* __restrict__ out, int n){
    int slice = blockIdx.y;
    const float* __restrict__ ys = y + (size_t)slice*n*8;
    float* __restrict__ os = out + (size_t)slice*n*8;
    int lane = threadIdx.x & 63;
    int wave = threadIdx.x >> 6;
    int g = lane >> 3, feat = lane & 7;
    float bv = bias[slice*8 + feat];
    int nbase = blockIdx.x*32 + wave*8;

    for(int i = 0; i < 8; ++i){
        int node = nbase + i;
        if(node >= n) return;
        int s0 = row_start[node];
        int s1 = row_start[node+1];
        float selfv = ys[(size_t)node*8 + feat];
        float acc0 = (g == 0) ? selfv : 0.f;
        float acc1 = 0.f;
        int j = s0;
        for(; j + 16 <= s1; j += 16){
            int sA = csr[j + g];
            int sB = csr[j + 8 + g];
            float vA = ys[(size_t)sA*8 + feat];
            float vB = ys[(size_t)sB*8 + feat];
            acc0 += vA; acc1 += vB;
        }
        {   // predicated tail (<16 edges)
            int eA = j + g, eB = j + 8 + g;
            bool kA = eA < s1, kB = eB < s1;
            int sA = kA ? csr[eA] : node;
            int sB = kB ? csr[eB] : node;
            float vA = ys[(size_t)sA*8 + feat];
            float vB = ys[(size_t)sB*8 + feat];
            if(kA) acc0 += vA;
            if(kB) acc1 += vB;
        }
        float a = acc0 + acc1;
        a += __shfl_xor(a, 8);
        a += __shfl_xor(a, 16);
        a += __shfl_xor(a, 32);
        if(g == 0){
            os[(size_t)node*8 + feat] = fmaxf(fmaf(a, dinv[node], bv), 0.f);
        }
    }
}

// ---------------- pooling over sorted batch (RM input) ----------------

__global__ void pool_kernel(const float* __restrict__ hjk, const int* __restrict__ batch,
                            int n, float* __restrict__ pooled){
    int c = threadIdx.x;
    int base = blockIdx.x*128;
    int end = base + 128; if(end > n) end = n;
    float acc = 0.f; int cur = -1;
    for(int i = base; i < end; ++i){
        int g = batch[i];
        if(g != cur){
            if(cur >= 0) atomicAdd(&pooled[cur*128 + c], acc);
            cur = g; acc = 0.f;
        }
        acc += hjk[(size_t)i*128 + c];
    }
    if(cur >= 0) atomicAdd(&pooled[cur*128 + c], acc);
}

// ---------------- MLP head ----------------

__global__ void head_kernel(const float* __restrict__ pooled,
                            const float* __restrict__ Wm1, const float* __restrict__ bm1,
                            const float* __restrict__ Wm2, const float* __restrict__ bm2,
                            float* __restrict__ out){
    __shared__ float p[128];
    __shared__ float tq[128];
    int g = blockIdx.x, j = threadIdx.x;
    p[j] = pooled[g*128 + j];
    __syncthreads();
    float a = bm1[j];
    for(int k = 0; k < 128; ++k) a = fmaf(p[k], Wm1[k*128 + j], a);
    tq[j] = fmaxf(a, 0.f);
    __syncthreads();
    if(j < 10){
        float o = bm2[j];
        for(int k = 0; k < 128; ++k) o = fmaf(tq[k], Wm2[k*10 + j], o);
        out[g*10 + j] = o;
    }
}

// ---------------- launch ----------------

extern "C" void kernel_launch(void* const* d_in, const int* in_sizes, int n_in,
                              void* d_out, int out_size, void* d_ws, size_t ws_size,
                              hipStream_t stream){
    const float* x    = (const float*)d_in[0];
    const int*   ei   = (const int*)  d_in[1];
    const int*   batch= (const int*)  d_in[2];
    const float* W0   = (const float*)d_in[3];
    const float* b0   = (const float*)d_in[4];
    const float* W1   = (const float*)d_in[5];
    const float* b1   = (const float*)d_in[6];
    const float* W2   = (const float*)d_in[7];
    const float* b2   = (const float*)d_in[8];
    const float* Wjk  = (const float*)d_in[9];
    const float* bjk  = (const float*)d_in[10];
    const float* Wm1  = (const float*)d_in[11];
    const float* bm1  = (const float*)d_in[12];
    const float* Wm2  = (const float*)d_in[13];
    const float* bm2  = (const float*)d_in[14];

    const int N = in_sizes[0] / 128;
    const int E = in_sizes[1] / 2;
    const int* src = ei;
    const int* dst = ei + E;

    char* ws = (char*)d_ws;
    size_t off = 0;
    auto take = [&](size_t bytes)->char*{
        char* p = ws + off; off = (off + bytes + 255) & ~(size_t)255; return p;
    };
    float* Y       = (float*)take((size_t)N*128*4);        // slice-major
    float* Habc    = (float*)take((size_t)3*N*128*4);      // three layer outputs, slice-major, contiguous
    float* HJK     = (float*)take((size_t)N*128*4);        // row-major
    float* dinv    = (float*)take((size_t)N*4);
    int*   deg     = (int*)  take((size_t)N*4);
    int*   cursor  = (int*)  take((size_t)N*4);
    int*   row_start=(int*)  take((size_t)(N+1)*4);
    int*   csr_src = (int*)  take((size_t)E*4);
    float* pooled  = (float*)take((size_t)512*128*4);
    int*   partials= (int*)  take((size_t)512*4);
    unsigned short* Whi = (unsigned short*)take((size_t)6*16384*2);
    unsigned short* Wlo = (unsigned short*)take((size_t)6*16384*2);

    hipMemsetAsync(deg,    0, (size_t)N*4, stream);
    hipMemsetAsync(cursor, 0, (size_t)N*4, stream);
    hipMemsetAsync(pooled, 0, (size_t)512*128*4, stream);

    int nb = (N + 255)/256;
    hist_kernel    <<<(E+255)/256, 256, 0, stream>>>(dst, E, deg);
    scan_part      <<<nb, 256, 0, stream>>>(deg, N, partials);
    scan_partials_k<<<1, 512, 0, stream>>>(partials, nb);
    scan_final     <<<nb, 256, 0, stream>>>(deg, N, partials, row_start, dinv);
    fill_csr       <<<(E+255)/256, 256, 0, stream>>>(src, dst, E, row_start, cursor, csr_src);
    prep_w_all     <<<384, 256, 0, stream>>>(W0, W1, W2, Wjk, Whi, Wlo);

    int gb = (N + 63)/64;
    dim3 ag((N + 31)/32, 16);

    // layer 1
    gemm_mfma<false,true,true><<<gb, 256, 0, stream>>>(x, Whi, Wlo, dinv, Y, N);
    aggregate_sm<<<ag, 256, 0, stream>>>(Y, row_start, csr_src, dinv, b0, Habc, N);
    // layer 2
    gemm_mfma<true,true,true><<<gb, 256, 0, stream>>>(Habc, Whi + 1*16384, Wlo + 1*16384, dinv, Y, N);
    aggregate_sm<<<ag, 256, 0, stream>>>(Y, row_start, csr_src, dinv, b1, Habc + (size_t)N*128, N);
    // layer 3
    gemm_mfma<true,true,true><<<gb, 256, 0, stream>>>(Habc + (size_t)N*128, Whi + 2*16384, Wlo + 2*16384, dinv, Y, N);
    aggregate_sm<<<ag, 256, 0, stream>>>(Y, row_start, csr_src, dinv, b2, Habc + (size_t)2*N*128, N);
    // JK projection (K=384, single pass)
    gemm_jk<<<gb, 256, 0, stream>>>(Habc, Whi + 3*16384, Wlo + 3*16384, bjk, HJK, N);

    pool_kernel<<<(N+127)/128, 128, 0, stream>>>(HJK, batch, N, pooled);
    head_kernel<<<512, 128, 0, stream>>>(pooled, Wm1, bm1, Wm2, bm2, (float*)d_out);
}

// Round 5
// 965.997 us; speedup vs baseline: 1.6772x; 1.6772x over previous
//
#include <hip/hip_runtime.h>

typedef __attribute__((ext_vector_type(8))) short bf16x8;
typedef __attribute__((ext_vector_type(4))) float f32x4;
typedef __attribute__((ext_vector_type(2))) float f32x2;

// ---------------- CSR build ----------------

__global__ void hist_kernel(const int* __restrict__ dst, int E, int* __restrict__ deg){
    int e = blockIdx.x*256 + threadIdx.x;
    if(e < E) atomicAdd(&deg[dst[e]], 1);
}

__global__ void scan_part(const int* __restrict__ deg, int n, int* __restrict__ partials){
    __shared__ int sm[256];
    int t = threadIdx.x;
    int idx = blockIdx.x*256 + t;
    sm[t] = (idx < n) ? deg[idx] : 0;
    __syncthreads();
    for(int s = 128; s > 0; s >>= 1){ if(t < s) sm[t] += sm[t+s]; __syncthreads(); }
    if(t == 0) partials[blockIdx.x] = sm[0];
}

__global__ void scan_partials_k(int* __restrict__ partials, int nb){
    __shared__ int sm[512];
    int t = threadIdx.x;
    int orig = (t < nb) ? partials[t] : 0;
    sm[t] = orig; __syncthreads();
    for(int s = 1; s < 512; s <<= 1){
        int add = (t >= s) ? sm[t-s] : 0;
        __syncthreads();
        sm[t] += add;
        __syncthreads();
    }
    if(t < nb) partials[t] = sm[t] - orig;   // exclusive
}

__global__ void scan_final(const int* __restrict__ deg, int n,
                           const int* __restrict__ partials, int* __restrict__ row_start,
                           float* __restrict__ dinv){
    __shared__ int sm[256];
    int t = threadIdx.x;
    int idx = blockIdx.x*256 + t;
    int orig = (idx < n) ? deg[idx] : 0;
    sm[t] = orig; __syncthreads();
    for(int s = 1; s < 256; s <<= 1){
        int add = (t >= s) ? sm[t-s] : 0;
        __syncthreads();
        sm[t] += add;
        __syncthreads();
    }
    int excl = partials[blockIdx.x] + sm[t] - orig;
    if(idx < n){
        row_start[idx] = excl;
        dinv[idx] = rsqrtf((float)orig + 1.0f);
    }
    if(idx == n-1) row_start[n] = excl + orig;   // == E
}

__global__ void fill_csr(const int* __restrict__ src, const int* __restrict__ dst, int E,
                         int* __restrict__ cursor, int* __restrict__ csr_src){
    int e = blockIdx.x*256 + threadIdx.x;
    if(e < E){
        int p = atomicAdd(&cursor[dst[e]], 1);   // cursor pre-copied from row_start
        csr_src[p] = src[e];
    }
}

// ---------------- weight prep: f32 -> transposed bf16 hi/lo ----------------
// m=0..2: square layers -> [col][128] at m*16384
// m=3..5: JK blocks     -> [col][384] at 3*16384 (col stride 384, k = (m-3)*128 + klocal)

__device__ inline void split_bf16(float x, unsigned short& h, unsigned short& l){
    union { float f; unsigned int u; } cv;
    cv.f = x;
    unsigned int u = cv.u;
    unsigned int rh = u + 0x7fffu + ((u >> 16) & 1u);
    h = (unsigned short)(rh >> 16);
    union { unsigned int u; float f; } hb;
    hb.u = ((unsigned int)h) << 16;
    float r = x - hb.f;
    cv.f = r;
    unsigned int u2 = cv.u;
    unsigned int rl = u2 + 0x7fffu + ((u2 >> 16) & 1u);
    l = (unsigned short)(rl >> 16);
}

__global__ void prep_w_all(const float* __restrict__ W0, const float* __restrict__ W1,
                           const float* __restrict__ W2, const float* __restrict__ Wjk,
                           unsigned short* __restrict__ hi, unsigned short* __restrict__ lo){
    int m = blockIdx.x >> 6;                         // 0..5
    int i = (blockIdx.x & 63)*256 + threadIdx.x;     // 0..16383
    const float* W = (m==0) ? W0 : (m==1) ? W1 : (m==2) ? W2 : (Wjk + (m-3)*16384);
    int k = i >> 7, c = i & 127;
    unsigned short h, l;
    split_bf16(W[i], h, l);
    size_t o = (m < 3) ? ((size_t)m*16384 + c*128 + k)
                       : ((size_t)3*16384 + c*384 + (m-3)*128 + k);
    hi[o] = h;
    lo[o] = l;
}

// ---------------- MFMA GEMM: out[n,128] = (in[n,128] @ W) * dinv_row   (all row-major) ----------------
// A frag (16x16x32): lane holds A[lane&15][(lane>>4)*8 + j]; C/D: col=lane&15, row=(lane>>4)*4+reg.

__global__ __launch_bounds__(256) void gemm_mfma(const float* __restrict__ in,
                                                 const unsigned short* __restrict__ Wt_hi,
                                                 const unsigned short* __restrict__ Wt_lo,
                                                 const float* __restrict__ dinv,
                                                 float* __restrict__ out, int n){
    int t = threadIdx.x;
    int wave = t >> 6, lane = t & 63;
    int r0 = blockIdx.x*64 + wave*16;
    if(r0 >= n) return;                  // n % 16 == 0
    int lr = lane & 15;
    int lk = (lane >> 4) * 8;

    f32x4 acc[8];
    #pragma unroll
    for(int c = 0; c < 8; ++c) acc[c] = (f32x4){0.f, 0.f, 0.f, 0.f};

    const float* arow = in + (size_t)(r0 + lr)*128;
    const unsigned short* bh = Wt_hi + lr*128 + lk;
    const unsigned short* bl = Wt_lo + lr*128 + lk;

    #pragma unroll
    for(int k0 = 0; k0 < 128; k0 += 32){
        f32x4 a0 = *(const f32x4*)(arow + k0 + lk);
        f32x4 a1 = *(const f32x4*)(arow + k0 + lk + 4);
        bf16x8 ahi, alo;
        #pragma unroll
        for(int j = 0; j < 4; ++j){
            unsigned short h, l;
            split_bf16(a0[j], h, l);
            ahi[j] = (short)h; alo[j] = (short)l;
            split_bf16(a1[j], h, l);
            ahi[j+4] = (short)h; alo[j+4] = (short)l;
        }
        #pragma unroll
        for(int c = 0; c < 8; ++c){
            bf16x8 bhi = *(const bf16x8*)(bh + c*2048 + k0);
            bf16x8 blo = *(const bf16x8*)(bl + c*2048 + k0);
            acc[c] = __builtin_amdgcn_mfma_f32_16x16x32_bf16(ahi, bhi, acc[c], 0, 0, 0);
            acc[c] = __builtin_amdgcn_mfma_f32_16x16x32_bf16(alo, bhi, acc[c], 0, 0, 0);
            acc[c] = __builtin_amdgcn_mfma_f32_16x16x32_bf16(ahi, blo, acc[c], 0, 0, 0);
        }
    }

    float dv[4];
    #pragma unroll
    for(int i = 0; i < 4; ++i) dv[i] = dinv[r0 + ((lane >> 4) << 2) + i];
    #pragma unroll
    for(int c = 0; c < 8; ++c){
        int ccol = c*16 + lr;
        #pragma unroll
        for(int i = 0; i < 4; ++i){
            int crow = r0 + ((lane >> 4) << 2) + i;
            out[(size_t)crow*128 + ccol] = acc[c][i] * dv[i];
        }
    }
}

// ---------------- JK GEMM: out[n,128] = [H0|H1|H2][n,384] @ Wjk + bjk (row-major) ----------------

__global__ __launch_bounds__(256) void gemm_jk(const float* __restrict__ habc,
                                               const unsigned short* __restrict__ Wt_hi,
                                               const unsigned short* __restrict__ Wt_lo,
                                               const float* __restrict__ bias,
                                               float* __restrict__ out, int n){
    int t = threadIdx.x;
    int wave = t >> 6, lane = t & 63;
    int r0 = blockIdx.x*64 + wave*16;
    if(r0 >= n) return;
    int lr = lane & 15;
    int lk = (lane >> 4) * 8;

    f32x4 acc[8];
    #pragma unroll
    for(int c = 0; c < 8; ++c) acc[c] = (f32x4){0.f, 0.f, 0.f, 0.f};

    const unsigned short* bh = Wt_hi + lr*384 + lk;
    const unsigned short* bl = Wt_lo + lr*384 + lk;

    #pragma unroll
    for(int kb3 = 0; kb3 < 3; ++kb3){
        const float* arow = habc + (size_t)kb3*n*128 + (size_t)(r0 + lr)*128;
        #pragma unroll
        for(int k0 = 0; k0 < 128; k0 += 32){
            f32x4 a0 = *(const f32x4*)(arow + k0 + lk);
            f32x4 a1 = *(const f32x4*)(arow + k0 + lk + 4);
            bf16x8 ahi, alo;
            #pragma unroll
            for(int j = 0; j < 4; ++j){
                unsigned short h, l;
                split_bf16(a0[j], h, l);
                ahi[j] = (short)h; alo[j] = (short)l;
                split_bf16(a1[j], h, l);
                ahi[j+4] = (short)h; alo[j+4] = (short)l;
            }
            int ko = kb3*128 + k0;
            #pragma unroll
            for(int c = 0; c < 8; ++c){
                bf16x8 bhi = *(const bf16x8*)(bh + c*6144 + ko);
                bf16x8 blo = *(const bf16x8*)(bl + c*6144 + ko);
                acc[c] = __builtin_amdgcn_mfma_f32_16x16x32_bf16(ahi, bhi, acc[c], 0, 0, 0);
                acc[c] = __builtin_amdgcn_mfma_f32_16x16x32_bf16(alo, bhi, acc[c], 0, 0, 0);
                acc[c] = __builtin_amdgcn_mfma_f32_16x16x32_bf16(ahi, blo, acc[c], 0, 0, 0);
            }
        }
    }

    #pragma unroll
    for(int c = 0; c < 8; ++c){
        int ccol = c*16 + lr;
        float bcol = bias[ccol];
        #pragma unroll
        for(int i = 0; i < 4; ++i){
            int crow = r0 + ((lane >> 4) << 2) + i;
            out[(size_t)crow*128 + ccol] = acc[c][i] + bcol;
        }
    }
}

// ---------------- pull aggregation: h[n] = relu(dinv[n]*(y[n] + sum_src y[src]) + b) ----------------
// One node per wave, full 512B row per gather instruction, 8 independent accumulators.

__global__ __launch_bounds__(256) void aggregate(const float* __restrict__ y, const int* __restrict__ row_start,
                                                 const int* __restrict__ csr_src, const float* __restrict__ dinv,
                                                 const float* __restrict__ bias, float* __restrict__ hout, int n){
    int wave = threadIdx.x >> 6;
    int lane = threadIdx.x & 63;
    int node = blockIdx.x*4 + wave;
    if(node >= n) return;
    const f32x2* __restrict__ y2 = (const f32x2*)y;
    int s0 = row_start[node];
    int s1 = row_start[node+1];

    f32x2 self = y2[(size_t)node*64 + lane];
    float ax[8], ay[8];
    ax[0] = self.x; ay[0] = self.y;
    #pragma unroll
    for(int u = 1; u < 8; ++u){ ax[u] = 0.f; ay[u] = 0.f; }

    int j = s0;
    for(; j + 8 <= s1; j += 8){
        int idx[8];
        #pragma unroll
        for(int u = 0; u < 8; ++u) idx[u] = csr_src[j+u];
        #pragma unroll
        for(int u = 0; u < 8; ++u){
            f32x2 v = y2[(size_t)idx[u]*64 + lane];
            ax[u] += v.x; ay[u] += v.y;
        }
    }
    int rem = s1 - j;                      // 0..7 predicated tail
    int idx[7];
    #pragma unroll
    for(int u = 0; u < 7; ++u) idx[u] = (u < rem) ? csr_src[j+u] : node;
    #pragma unroll
    for(int u = 0; u < 7; ++u){
        f32x2 v = y2[(size_t)idx[u]*64 + lane];
        if(u < rem){ ax[u] += v.x; ay[u] += v.y; }
    }

    float s_x = ((ax[0]+ax[1]) + (ax[2]+ax[3])) + ((ax[4]+ax[5]) + (ax[6]+ax[7]));
    float s_y = ((ay[0]+ay[1]) + (ay[2]+ay[3])) + ((ay[4]+ay[5]) + (ay[6]+ay[7]));
    float dn = dinv[node];
    float bx = bias[lane*2], by = bias[lane*2+1];
    f32x2 r;
    r.x = fmaxf(fmaf(s_x, dn, bx), 0.f);
    r.y = fmaxf(fmaf(s_y, dn, by), 0.f);
    __builtin_nontemporal_store(r, (f32x2*)&hout[(size_t)node*128 + lane*2]);
}

// ---------------- pooling over sorted batch ----------------

__global__ void pool_kernel(const float* __restrict__ hjk, const int* __restrict__ batch,
                            int n, float* __restrict__ pooled){
    int c = threadIdx.x;
    int base = blockIdx.x*128;
    int end = base + 128; if(end > n) end = n;
    float acc = 0.f; int cur = -1;
    for(int i = base; i < end; ++i){
        int g = batch[i];
        if(g != cur){
            if(cur >= 0) atomicAdd(&pooled[cur*128 + c], acc);
            cur = g; acc = 0.f;
        }
        acc += hjk[(size_t)i*128 + c];
    }
    if(cur >= 0) atomicAdd(&pooled[cur*128 + c], acc);
}

// ---------------- MLP head ----------------

__global__ void head_kernel(const float* __restrict__ pooled,
                            const float* __restrict__ Wm1, const float* __restrict__ bm1,
                            const float* __restrict__ Wm2, const float* __restrict__ bm2,
                            float* __restrict__ out){
    __shared__ float p[128];
    __shared__ float tq[128];
    int g = blockIdx.x, j = threadIdx.x;
    p[j] = pooled[g*128 + j];
    __syncthreads();
    float a = bm1[j];
    for(int k = 0; k < 128; ++k) a = fmaf(p[k], Wm1[k*128 + j], a);
    tq[j] = fmaxf(a, 0.f);
    __syncthreads();
    if(j < 10){
        float o = bm2[j];
        for(int k = 0; k < 128; ++k) o = fmaf(tq[k], Wm2[k*10 + j], o);
        out[g*10 + j] = o;
    }
}

// ---------------- launch ----------------

extern "C" void kernel_launch(void* const* d_in, const int* in_sizes, int n_in,
                              void* d_out, int out_size, void* d_ws, size_t ws_size,
                              hipStream_t stream){
    const float* x    = (const float*)d_in[0];
    const int*   ei   = (const int*)  d_in[1];
    const int*   batch= (const int*)  d_in[2];
    const float* W0   = (const float*)d_in[3];
    const float* b0   = (const float*)d_in[4];
    const float* W1   = (const float*)d_in[5];
    const float* b1   = (const float*)d_in[6];
    const float* W2   = (const float*)d_in[7];
    const float* b2   = (const float*)d_in[8];
    const float* Wjk  = (const float*)d_in[9];
    const float* bjk  = (const float*)d_in[10];
    const float* Wm1  = (const float*)d_in[11];
    const float* bm1  = (const float*)d_in[12];
    const float* Wm2  = (const float*)d_in[13];
    const float* bm2  = (const float*)d_in[14];

    const int N = in_sizes[0] / 128;
    const int E = in_sizes[1] / 2;
    const int* src = ei;
    const int* dst = ei + E;

    char* ws = (char*)d_ws;
    size_t off = 0;
    auto take = [&](size_t bytes)->char*{
        char* p = ws + off; off = (off + bytes + 255) & ~(size_t)255; return p;
    };
    float* Y       = (float*)take((size_t)N*128*4);        // row-major
    float* Habc    = (float*)take((size_t)3*N*128*4);      // [3][N][128] row-major, contiguous
    float* HJK     = (float*)take((size_t)N*128*4);
    float* dinv    = (float*)take((size_t)N*4);
    int*   deg     = (int*)  take((size_t)N*4);
    int*   cursor  = (int*)  take((size_t)N*4);
    int*   row_start=(int*)  take((size_t)(N+1)*4);
    int*   csr_src = (int*)  take((size_t)E*4 + 64);       // +pad for tail reads
    float* pooled  = (float*)take((size_t)512*128*4);
    int*   partials= (int*)  take((size_t)512*4);
    unsigned short* Whi = (unsigned short*)take((size_t)(3*16384 + 3*16384)*2);
    unsigned short* Wlo = (unsigned short*)take((size_t)(3*16384 + 3*16384)*2);

    (void)hipMemsetAsync(deg,    0, (size_t)N*4, stream);
    (void)hipMemsetAsync(pooled, 0, (size_t)512*128*4, stream);

    int nb = (N + 255)/256;
    hist_kernel    <<<(E+255)/256, 256, 0, stream>>>(dst, E, deg);
    scan_part      <<<nb, 256, 0, stream>>>(deg, N, partials);
    scan_partials_k<<<1, 512, 0, stream>>>(partials, nb);
    scan_final     <<<nb, 256, 0, stream>>>(deg, N, partials, row_start, dinv);
    (void)hipMemcpyAsync(cursor, row_start, (size_t)N*4, hipMemcpyDeviceToDevice, stream);
    fill_csr       <<<(E+255)/256, 256, 0, stream>>>(src, dst, E, cursor, csr_src);
    prep_w_all     <<<384, 256, 0, stream>>>(W0, W1, W2, Wjk, Whi, Wlo);

    int gb = (N + 63)/64;
    int ab = (N + 3)/4;
    float* H0 = Habc;
    float* H1 = Habc + (size_t)N*128;
    float* H2 = Habc + (size_t)2*N*128;

    // layer 1
    gemm_mfma<<<gb, 256, 0, stream>>>(x,  Whi,           Wlo,           dinv, Y, N);
    aggregate<<<ab, 256, 0, stream>>>(Y, row_start, csr_src, dinv, b0, H0, N);
    // layer 2
    gemm_mfma<<<gb, 256, 0, stream>>>(H0, Whi + 1*16384, Wlo + 1*16384, dinv, Y, N);
    aggregate<<<ab, 256, 0, stream>>>(Y, row_start, csr_src, dinv, b1, H1, N);
    // layer 3
    gemm_mfma<<<gb, 256, 0, stream>>>(H1, Whi + 2*16384, Wlo + 2*16384, dinv, Y, N);
    aggregate<<<ab, 256, 0, stream>>>(Y, row_start, csr_src, dinv, b2, H2, N);
    // JK projection (K=384, single pass)
    gemm_jk<<<gb, 256, 0, stream>>>(Habc, Whi + 3*16384, Wlo + 3*16384, bjk, HJK, N);

    pool_kernel<<<(N+127)/128, 128, 0, stream>>>(HJK, batch, N, pooled);
    head_kernel<<<512, 128, 0, stream>>>(pooled, Wm1, bm1, Wm2, bm2, (float*)d_out);
}

// Round 6
// 775.141 us; speedup vs baseline: 2.0902x; 1.2462x over previous
//
#include <hip/hip_runtime.h>

typedef __attribute__((ext_vector_type(8))) short bf16x8;
typedef __attribute__((ext_vector_type(4))) float f32x4;
typedef __attribute__((ext_vector_type(2))) float f32x2;

// ---------------- CSR build ----------------

__global__ void hist_kernel(const int* __restrict__ dst, int E, int* __restrict__ deg){
    int e = blockIdx.x*256 + threadIdx.x;
    if(e < E) atomicAdd(&deg[dst[e]], 1);
}

__global__ void scan_part(const int* __restrict__ deg, int n, int* __restrict__ partials){
    __shared__ int sm[256];
    int t = threadIdx.x;
    int idx = blockIdx.x*256 + t;
    sm[t] = (idx < n) ? deg[idx] : 0;
    __syncthreads();
    for(int s = 128; s > 0; s >>= 1){ if(t < s) sm[t] += sm[t+s]; __syncthreads(); }
    if(t == 0) partials[blockIdx.x] = sm[0];
}

__global__ void scan_partials_k(int* __restrict__ partials, int nb){
    __shared__ int sm[512];
    int t = threadIdx.x;
    int orig = (t < nb) ? partials[t] : 0;
    sm[t] = orig; __syncthreads();
    for(int s = 1; s < 512; s <<= 1){
        int add = (t >= s) ? sm[t-s] : 0;
        __syncthreads();
        sm[t] += add;
        __syncthreads();
    }
    if(t < nb) partials[t] = sm[t] - orig;   // exclusive
}

__global__ void scan_final(const int* __restrict__ deg, int n,
                           const int* __restrict__ partials, int* __restrict__ row_start,
                           float* __restrict__ dinv){
    __shared__ int sm[256];
    int t = threadIdx.x;
    int idx = blockIdx.x*256 + t;
    int orig = (idx < n) ? deg[idx] : 0;
    sm[t] = orig; __syncthreads();
    for(int s = 1; s < 256; s <<= 1){
        int add = (t >= s) ? sm[t-s] : 0;
        __syncthreads();
        sm[t] += add;
        __syncthreads();
    }
    int excl = partials[blockIdx.x] + sm[t] - orig;
    if(idx < n){
        row_start[idx] = excl;
        dinv[idx] = rsqrtf((float)orig + 1.0f);
    }
    if(idx == n-1) row_start[n] = excl + orig;   // == E
}

__global__ void fill_csr(const int* __restrict__ src, const int* __restrict__ dst, int E,
                         int* __restrict__ cursor, int* __restrict__ csr_src){
    int e = blockIdx.x*256 + threadIdx.x;
    if(e < E){
        int p = atomicAdd(&cursor[dst[e]], 1);   // cursor pre-copied from row_start
        csr_src[p] = src[e];
    }
}

// ---------------- weight prep: f32 -> transposed, XOR-swizzled bf16 hi/lo ----------------
// Six [128][128] tables (JK split into its 3 K-blocks), each stored [col][k] with
// k-index swizzle (k ^ ((col&7)<<3)) so LDS-staged ds_read_b128 is 2-way conflict (free).

__device__ inline void split_bf16(float x, unsigned short& h, unsigned short& l){
    union { float f; unsigned int u; } cv;
    cv.f = x;
    unsigned int u = cv.u;
    unsigned int rh = u + 0x7fffu + ((u >> 16) & 1u);
    h = (unsigned short)(rh >> 16);
    union { unsigned int u; float f; } hb;
    hb.u = ((unsigned int)h) << 16;
    float r = x - hb.f;
    cv.f = r;
    unsigned int u2 = cv.u;
    unsigned int rl = u2 + 0x7fffu + ((u2 >> 16) & 1u);
    l = (unsigned short)(rl >> 16);
}

__global__ void prep_w_all(const float* __restrict__ W0, const float* __restrict__ W1,
                           const float* __restrict__ W2, const float* __restrict__ Wjk,
                           unsigned short* __restrict__ hi, unsigned short* __restrict__ lo){
    int m = blockIdx.x >> 6;                         // 0..5
    int i = (blockIdx.x & 63)*256 + threadIdx.x;     // 0..16383
    const float* W = (m==0) ? W0 : (m==1) ? W1 : (m==2) ? W2 : (Wjk + (m-3)*16384);
    int k = i >> 7, c = i & 127;                     // W is [k][c]
    unsigned short h, l;
    split_bf16(W[i], h, l);
    size_t o = (size_t)m*16384 + c*128 + (k ^ ((c & 7) << 3));
    hi[o] = h;
    lo[o] = l;
}

// ---------------- MFMA GEMM: out[n,128] = (in[n,128] @ W) * dinv_row   (row-major) ----------------
// B staged in LDS (64KB: hi+lo), shared by the block's 4 waves.
// A frag (16x16x32): lane holds A[lane&15][(lane>>4)*8 + j]; C/D: col=lane&15, row=(lane>>4)*4+reg.

__global__ __launch_bounds__(256) void gemm_mfma(const float* __restrict__ in,
                                                 const unsigned short* __restrict__ Wt_hi,
                                                 const unsigned short* __restrict__ Wt_lo,
                                                 const float* __restrict__ dinv,
                                                 float* __restrict__ out, int n){
    __shared__ __align__(16) unsigned short Bs[32768];   // [hi 16384][lo 16384] elements
    int t = threadIdx.x;
    int lane = t & 63;
    int r0 = blockIdx.x*64 + (t >> 6)*16;
    int lr = lane & 15;
    int lk = (lane >> 4) * 8;

    {   // stage B: linear 64KB copy (tables pre-swizzled)
        uint4* d = (uint4*)Bs;
        const uint4* sH = (const uint4*)Wt_hi;
        const uint4* sL = (const uint4*)Wt_lo;
        #pragma unroll
        for(int i = 0; i < 8; ++i){
            d[t + i*256]        = sH[t + i*256];
            d[2048 + t + i*256] = sL[t + i*256];
        }
    }
    __syncthreads();

    f32x4 acc[8];
    #pragma unroll
    for(int c = 0; c < 8; ++c) acc[c] = (f32x4){0.f, 0.f, 0.f, 0.f};

    int arow_i = r0 + lr; if(arow_i > n-1) arow_i = n-1;    // clamp: all waves reach barriers
    const float* arow = in + (size_t)arow_i*128;

    #pragma unroll
    for(int k0 = 0; k0 < 128; k0 += 32){
        f32x4 a0 = *(const f32x4*)(arow + k0 + lk);
        f32x4 a1 = *(const f32x4*)(arow + k0 + lk + 4);
        bf16x8 ahi, alo;
        #pragma unroll
        for(int j = 0; j < 4; ++j){
            unsigned short h, l;
            split_bf16(a0[j], h, l);
            ahi[j] = (short)h; alo[j] = (short)l;
            split_bf16(a1[j], h, l);
            ahi[j+4] = (short)h; alo[j+4] = (short)l;
        }
        int kidx = (k0 + lk) ^ ((lr & 7) << 3);
        #pragma unroll
        for(int c = 0; c < 8; ++c){
            bf16x8 bhi = *(const bf16x8*)&Bs[(c*16 + lr)*128 + kidx];
            bf16x8 blo = *(const bf16x8*)&Bs[16384 + (c*16 + lr)*128 + kidx];
            acc[c] = __builtin_amdgcn_mfma_f32_16x16x32_bf16(ahi, bhi, acc[c], 0, 0, 0);
            acc[c] = __builtin_amdgcn_mfma_f32_16x16x32_bf16(alo, bhi, acc[c], 0, 0, 0);
            acc[c] = __builtin_amdgcn_mfma_f32_16x16x32_bf16(ahi, blo, acc[c], 0, 0, 0);
        }
    }

    float dv[4];
    #pragma unroll
    for(int i = 0; i < 4; ++i){
        int cr = r0 + ((lane >> 4) << 2) + i; if(cr > n-1) cr = n-1;
        dv[i] = dinv[cr];
    }
    #pragma unroll
    for(int c = 0; c < 8; ++c){
        int ccol = c*16 + lr;
        #pragma unroll
        for(int i = 0; i < 4; ++i){
            int crow = r0 + ((lane >> 4) << 2) + i;
            if(crow < n) out[(size_t)crow*128 + ccol] = acc[c][i] * dv[i];
        }
    }
}

// ---------------- JK GEMM: out[n,128] = [H0|H1|H2][n,384] @ Wjk + bjk ----------------
// Three staged 64KB B-phases reusing one LDS buffer.

__global__ __launch_bounds__(256) void gemm_jk(const float* __restrict__ habc,
                                               const unsigned short* __restrict__ Whi,
                                               const unsigned short* __restrict__ Wlo,
                                               const float* __restrict__ bias,
                                               float* __restrict__ out, int n){
    __shared__ __align__(16) unsigned short Bs[32768];
    int t = threadIdx.x;
    int lane = t & 63;
    int r0 = blockIdx.x*64 + (t >> 6)*16;
    int lr = lane & 15;
    int lk = (lane >> 4) * 8;

    f32x4 acc[8];
    #pragma unroll
    for(int c = 0; c < 8; ++c) acc[c] = (f32x4){0.f, 0.f, 0.f, 0.f};

    int arow_i = r0 + lr; if(arow_i > n-1) arow_i = n-1;

    for(int kb3 = 0; kb3 < 3; ++kb3){
        __syncthreads();                 // previous phase's reads complete
        {
            uint4* d = (uint4*)Bs;
            const uint4* sH = (const uint4*)(Whi + (size_t)(3 + kb3)*16384);
            const uint4* sL = (const uint4*)(Wlo + (size_t)(3 + kb3)*16384);
            #pragma unroll
            for(int i = 0; i < 8; ++i){
                d[t + i*256]        = sH[t + i*256];
                d[2048 + t + i*256] = sL[t + i*256];
            }
        }
        __syncthreads();

        const float* arow = habc + (size_t)kb3*n*128 + (size_t)arow_i*128;
        #pragma unroll
        for(int k0 = 0; k0 < 128; k0 += 32){
            f32x4 a0 = *(const f32x4*)(arow + k0 + lk);
            f32x4 a1 = *(const f32x4*)(arow + k0 + lk + 4);
            bf16x8 ahi, alo;
            #pragma unroll
            for(int j = 0; j < 4; ++j){
                unsigned short h, l;
                split_bf16(a0[j], h, l);
                ahi[j] = (short)h; alo[j] = (short)l;
                split_bf16(a1[j], h, l);
                ahi[j+4] = (short)h; alo[j+4] = (short)l;
            }
            int kidx = (k0 + lk) ^ ((lr & 7) << 3);
            #pragma unroll
            for(int c = 0; c < 8; ++c){
                bf16x8 bhi = *(const bf16x8*)&Bs[(c*16 + lr)*128 + kidx];
                bf16x8 blo = *(const bf16x8*)&Bs[16384 + (c*16 + lr)*128 + kidx];
                acc[c] = __builtin_amdgcn_mfma_f32_16x16x32_bf16(ahi, bhi, acc[c], 0, 0, 0);
                acc[c] = __builtin_amdgcn_mfma_f32_16x16x32_bf16(alo, bhi, acc[c], 0, 0, 0);
                acc[c] = __builtin_amdgcn_mfma_f32_16x16x32_bf16(ahi, blo, acc[c], 0, 0, 0);
            }
        }
    }

    #pragma unroll
    for(int c = 0; c < 8; ++c){
        int ccol = c*16 + lr;
        float bcol = bias[ccol];
        #pragma unroll
        for(int i = 0; i < 4; ++i){
            int crow = r0 + ((lane >> 4) << 2) + i;
            if(crow < n) out[(size_t)crow*128 + ccol] = acc[c][i] + bcol;
        }
    }
}

// ---------------- pull aggregation: h[n] = relu(dinv[n]*(y[n] + sum_src y[src]) + b) ----------------
// One node per wave, full 512B row per gather instruction, 8 independent accumulators.

__global__ __launch_bounds__(256) void aggregate(const float* __restrict__ y, const int* __restrict__ row_start,
                                                 const int* __restrict__ csr_src, const float* __restrict__ dinv,
                                                 const float* __restrict__ bias, float* __restrict__ hout, int n){
    int wave = threadIdx.x >> 6;
    int lane = threadIdx.x & 63;
    int node = blockIdx.x*4 + wave;
    if(node >= n) return;
    const f32x2* __restrict__ y2 = (const f32x2*)y;
    int s0 = row_start[node];
    int s1 = row_start[node+1];

    f32x2 self = y2[(size_t)node*64 + lane];
    float ax[8], ay[8];
    ax[0] = self.x; ay[0] = self.y;
    #pragma unroll
    for(int u = 1; u < 8; ++u){ ax[u] = 0.f; ay[u] = 0.f; }

    int j = s0;
    for(; j + 8 <= s1; j += 8){
        int idx[8];
        #pragma unroll
        for(int u = 0; u < 8; ++u) idx[u] = csr_src[j+u];
        #pragma unroll
        for(int u = 0; u < 8; ++u){
            f32x2 v = y2[(size_t)idx[u]*64 + lane];
            ax[u] += v.x; ay[u] += v.y;
        }
    }
    int rem = s1 - j;                      // 0..7 predicated tail
    int idx[7];
    #pragma unroll
    for(int u = 0; u < 7; ++u) idx[u] = (u < rem) ? csr_src[j+u] : node;
    #pragma unroll
    for(int u = 0; u < 7; ++u){
        f32x2 v = y2[(size_t)idx[u]*64 + lane];
        if(u < rem){ ax[u] += v.x; ay[u] += v.y; }
    }

    float s_x = ((ax[0]+ax[1]) + (ax[2]+ax[3])) + ((ax[4]+ax[5]) + (ax[6]+ax[7]));
    float s_y = ((ay[0]+ay[1]) + (ay[2]+ay[3])) + ((ay[4]+ay[5]) + (ay[6]+ay[7]));
    float dn = dinv[node];
    float bx = bias[lane*2], by = bias[lane*2+1];
    f32x2 r;
    r.x = fmaxf(fmaf(s_x, dn, bx), 0.f);
    r.y = fmaxf(fmaf(s_y, dn, by), 0.f);
    __builtin_nontemporal_store(r, (f32x2*)&hout[(size_t)node*128 + lane*2]);
}

// ---------------- pooling over sorted batch ----------------

__global__ void pool_kernel(const float* __restrict__ hjk, const int* __restrict__ batch,
                            int n, float* __restrict__ pooled){
    int c = threadIdx.x;
    int base = blockIdx.x*128;
    int end = base + 128; if(end > n) end = n;
    float acc = 0.f; int cur = -1;
    for(int i = base; i < end; ++i){
        int g = batch[i];
        if(g != cur){
            if(cur >= 0) atomicAdd(&pooled[cur*128 + c], acc);
            cur = g; acc = 0.f;
        }
        acc += hjk[(size_t)i*128 + c];
    }
    if(cur >= 0) atomicAdd(&pooled[cur*128 + c], acc);
}

// ---------------- MLP head ----------------

__global__ void head_kernel(const float* __restrict__ pooled,
                            const float* __restrict__ Wm1, const float* __restrict__ bm1,
                            const float* __restrict__ Wm2, const float* __restrict__ bm2,
                            float* __restrict__ out){
    __shared__ float p[128];
    __shared__ float tq[128];
    int g = blockIdx.x, j = threadIdx.x;
    p[j] = pooled[g*128 + j];
    __syncthreads();
    float a = bm1[j];
    for(int k = 0; k < 128; ++k) a = fmaf(p[k], Wm1[k*128 + j], a);
    tq[j] = fmaxf(a, 0.f);
    __syncthreads();
    if(j < 10){
        float o = bm2[j];
        for(int k = 0; k < 128; ++k) o = fmaf(tq[k], Wm2[k*10 + j], o);
        out[g*10 + j] = o;
    }
}

// ---------------- launch ----------------

extern "C" void kernel_launch(void* const* d_in, const int* in_sizes, int n_in,
                              void* d_out, int out_size, void* d_ws, size_t ws_size,
                              hipStream_t stream){
    const float* x    = (const float*)d_in[0];
    const int*   ei   = (const int*)  d_in[1];
    const int*   batch= (const int*)  d_in[2];
    const float* W0   = (const float*)d_in[3];
    const float* b0   = (const float*)d_in[4];
    const float* W1   = (const float*)d_in[5];
    const float* b1   = (const float*)d_in[6];
    const float* W2   = (const float*)d_in[7];
    const float* b2   = (const float*)d_in[8];
    const float* Wjk  = (const float*)d_in[9];
    const float* bjk  = (const float*)d_in[10];
    const float* Wm1  = (const float*)d_in[11];
    const float* bm1  = (const float*)d_in[12];
    const float* Wm2  = (const float*)d_in[13];
    const float* bm2  = (const float*)d_in[14];

    const int N = in_sizes[0] / 128;
    const int E = in_sizes[1] / 2;
    const int* src = ei;
    const int* dst = ei + E;

    char* ws = (char*)d_ws;
    size_t off = 0;
    auto take = [&](size_t bytes)->char*{
        char* p = ws + off; off = (off + bytes + 255) & ~(size_t)255; return p;
    };
    float* Y       = (float*)take((size_t)N*128*4);        // row-major
    float* Habc    = (float*)take((size_t)3*N*128*4);      // [3][N][128] row-major, contiguous
    float* HJK     = (float*)take((size_t)N*128*4);
    float* dinv    = (float*)take((size_t)N*4);
    int*   deg     = (int*)  take((size_t)N*4);
    int*   cursor  = (int*)  take((size_t)N*4);
    int*   row_start=(int*)  take((size_t)(N+1)*4);
    int*   csr_src = (int*)  take((size_t)E*4 + 64);       // +pad for tail reads
    float* pooled  = (float*)take((size_t)512*128*4);
    int*   partials= (int*)  take((size_t)512*4);
    unsigned short* Whi = (unsigned short*)take((size_t)6*16384*2);
    unsigned short* Wlo = (unsigned short*)take((size_t)6*16384*2);

    (void)hipMemsetAsync(deg,    0, (size_t)N*4, stream);
    (void)hipMemsetAsync(pooled, 0, (size_t)512*128*4, stream);

    int nb = (N + 255)/256;
    hist_kernel    <<<(E+255)/256, 256, 0, stream>>>(dst, E, deg);
    scan_part      <<<nb, 256, 0, stream>>>(deg, N, partials);
    scan_partials_k<<<1, 512, 0, stream>>>(partials, nb);
    scan_final     <<<nb, 256, 0, stream>>>(deg, N, partials, row_start, dinv);
    (void)hipMemcpyAsync(cursor, row_start, (size_t)N*4, hipMemcpyDeviceToDevice, stream);
    fill_csr       <<<(E+255)/256, 256, 0, stream>>>(src, dst, E, cursor, csr_src);
    prep_w_all     <<<384, 256, 0, stream>>>(W0, W1, W2, Wjk, Whi, Wlo);

    int gb = (N + 63)/64;
    int ab = (N + 3)/4;
    float* H0 = Habc;
    float* H1 = Habc + (size_t)N*128;
    float* H2 = Habc + (size_t)2*N*128;

    // layer 1
    gemm_mfma<<<gb, 256, 0, stream>>>(x,  Whi,           Wlo,           dinv, Y, N);
    aggregate<<<ab, 256, 0, stream>>>(Y, row_start, csr_src, dinv, b0, H0, N);
    // layer 2
    gemm_mfma<<<gb, 256, 0, stream>>>(H0, Whi + 1*16384, Wlo + 1*16384, dinv, Y, N);
    aggregate<<<ab, 256, 0, stream>>>(Y, row_start, csr_src, dinv, b1, H1, N);
    // layer 3
    gemm_mfma<<<gb, 256, 0, stream>>>(H1, Whi + 2*16384, Wlo + 2*16384, dinv, Y, N);
    aggregate<<<ab, 256, 0, stream>>>(Y, row_start, csr_src, dinv, b2, H2, N);
    // JK projection (K=384, single pass, 3 staged B-phases)
    gemm_jk<<<gb, 256, 0, stream>>>(Habc, Whi, Wlo, bjk, HJK, N);

    pool_kernel<<<(N+127)/128, 128, 0, stream>>>(HJK, batch, N, pooled);
    head_kernel<<<512, 128, 0, stream>>>(pooled, Wm1, bm1, Wm2, bm2, (float*)d_out);
}

// Round 7
// 593.883 us; speedup vs baseline: 2.7281x; 1.3052x over previous
//
#include <hip/hip_runtime.h>

typedef __attribute__((ext_vector_type(8))) short bf16x8;
typedef __attribute__((ext_vector_type(4))) float f32x4;
typedef __attribute__((ext_vector_type(2))) float f32x2;

__device__ inline unsigned short f2b(float x){
    union{float f; unsigned int u;} c; c.f = x;
    unsigned int r = c.u + 0x7fffu + ((c.u >> 16) & 1u);
    return (unsigned short)(r >> 16);
}
__device__ inline float b2f_lo(unsigned int u){       // low bf16 of packed pair
    union{unsigned int u; float f;} c; c.u = u << 16; return c.f;
}
__device__ inline float b2f_hi(unsigned int u){       // high bf16 of packed pair
    union{unsigned int u; float f;} c; c.u = u & 0xffff0000u; return c.f;
}

// ---------------- CSR build ----------------

__global__ void hist_kernel(const int* __restrict__ dst, int E, int* __restrict__ deg){
    int e = blockIdx.x*256 + threadIdx.x;
    if(e < E) atomicAdd(&deg[dst[e]], 1);
}

__global__ void scan_part(const int* __restrict__ deg, int n, int* __restrict__ partials){
    __shared__ int sm[256];
    int t = threadIdx.x;
    int idx = blockIdx.x*256 + t;
    sm[t] = (idx < n) ? deg[idx] : 0;
    __syncthreads();
    for(int s = 128; s > 0; s >>= 1){ if(t < s) sm[t] += sm[t+s]; __syncthreads(); }
    if(t == 0) partials[blockIdx.x] = sm[0];
}

__global__ void scan_partials_k(int* __restrict__ partials, int nb){
    __shared__ int sm[512];
    int t = threadIdx.x;
    int orig = (t < nb) ? partials[t] : 0;
    sm[t] = orig; __syncthreads();
    for(int s = 1; s < 512; s <<= 1){
        int add = (t >= s) ? sm[t-s] : 0;
        __syncthreads();
        sm[t] += add;
        __syncthreads();
    }
    if(t < nb) partials[t] = sm[t] - orig;   // exclusive
}

__global__ void scan_final(const int* __restrict__ deg, int n,
                           const int* __restrict__ partials, int* __restrict__ row_start,
                           float* __restrict__ dinv){
    __shared__ int sm[256];
    int t = threadIdx.x;
    int idx = blockIdx.x*256 + t;
    int orig = (idx < n) ? deg[idx] : 0;
    sm[t] = orig; __syncthreads();
    for(int s = 1; s < 256; s <<= 1){
        int add = (t >= s) ? sm[t-s] : 0;
        __syncthreads();
        sm[t] += add;
        __syncthreads();
    }
    int excl = partials[blockIdx.x] + sm[t] - orig;
    if(idx < n){
        row_start[idx] = excl;
        dinv[idx] = rsqrtf((float)orig + 1.0f);
    }
    if(idx == n-1) row_start[n] = excl + orig;   // == E
}

__global__ void fill_csr(const int* __restrict__ src, const int* __restrict__ dst, int E,
                         int* __restrict__ cursor, int* __restrict__ csr_src){
    int e = blockIdx.x*256 + threadIdx.x;
    if(e < E){
        int p = atomicAdd(&cursor[dst[e]], 1);   // cursor pre-copied from row_start
        csr_src[p] = src[e];
    }
}

// ---------------- weight prep: f32 -> transposed, XOR-swizzled bf16 hi/lo ----------------

__device__ inline void split_bf16(float x, unsigned short& h, unsigned short& l){
    union { float f; unsigned int u; } cv;
    cv.f = x;
    unsigned int u = cv.u;
    unsigned int rh = u + 0x7fffu + ((u >> 16) & 1u);
    h = (unsigned short)(rh >> 16);
    union { unsigned int u; float f; } hb;
    hb.u = ((unsigned int)h) << 16;
    float r = x - hb.f;
    cv.f = r;
    unsigned int u2 = cv.u;
    unsigned int rl = u2 + 0x7fffu + ((u2 >> 16) & 1u);
    l = (unsigned short)(rl >> 16);
}

__global__ void prep_w_all(const float* __restrict__ W0, const float* __restrict__ W1,
                           const float* __restrict__ W2, const float* __restrict__ Wjk,
                           unsigned short* __restrict__ hi, unsigned short* __restrict__ lo){
    int m = blockIdx.x >> 6;                         // 0..5
    int i = (blockIdx.x & 63)*256 + threadIdx.x;     // 0..16383
    const float* W = (m==0) ? W0 : (m==1) ? W1 : (m==2) ? W2 : (Wjk + (m-3)*16384);
    int k = i >> 7, c = i & 127;                     // W is [k][c]
    unsigned short h, l;
    split_bf16(W[i], h, l);
    size_t o = (size_t)m*16384 + c*128 + (k ^ ((c & 7) << 3));
    hi[o] = h;
    lo[o] = l;
}

// ---------------- GEMM (layer 1): out_bf16[n,128] = (x_f32[n,128] @ W) * dinv_row ----------------
// B staged in LDS (64KB hi+lo, pre-swizzled). Split-A 3-MFMA for f32-grade accuracy.
// A frag (16x16x32): lane holds A[lane&15][(lane>>4)*8+j]; C/D: col=lane&15, row=(lane>>4)*4+reg.

__global__ __launch_bounds__(256) void gemm_f32A(const float* __restrict__ in,
                                                 const unsigned short* __restrict__ Wt_hi,
                                                 const unsigned short* __restrict__ Wt_lo,
                                                 const float* __restrict__ dinv,
                                                 unsigned short* __restrict__ out, int n){
    __shared__ __align__(16) unsigned short Bs[32768];
    int t = threadIdx.x;
    int lane = t & 63;
    int r0 = blockIdx.x*64 + (t >> 6)*16;
    int lr = lane & 15;
    int lk = (lane >> 4) * 8;

    {
        uint4* d = (uint4*)Bs;
        const uint4* sH = (const uint4*)Wt_hi;
        const uint4* sL = (const uint4*)Wt_lo;
        #pragma unroll
        for(int i = 0; i < 8; ++i){
            d[t + i*256]        = sH[t + i*256];
            d[2048 + t + i*256] = sL[t + i*256];
        }
    }
    __syncthreads();

    f32x4 acc[8];
    #pragma unroll
    for(int c = 0; c < 8; ++c) acc[c] = (f32x4){0.f, 0.f, 0.f, 0.f};

    int arow_i = r0 + lr; if(arow_i > n-1) arow_i = n-1;
    const float* arow = in + (size_t)arow_i*128;

    #pragma unroll
    for(int k0 = 0; k0 < 128; k0 += 32){
        f32x4 a0 = *(const f32x4*)(arow + k0 + lk);
        f32x4 a1 = *(const f32x4*)(arow + k0 + lk + 4);
        bf16x8 ahi, alo;
        #pragma unroll
        for(int j = 0; j < 4; ++j){
            unsigned short h, l;
            split_bf16(a0[j], h, l);
            ahi[j] = (short)h; alo[j] = (short)l;
            split_bf16(a1[j], h, l);
            ahi[j+4] = (short)h; alo[j+4] = (short)l;
        }
        int kidx = (k0 + lk) ^ ((lr & 7) << 3);
        #pragma unroll
        for(int c = 0; c < 8; ++c){
            bf16x8 bhi = *(const bf16x8*)&Bs[(c*16 + lr)*128 + kidx];
            bf16x8 blo = *(const bf16x8*)&Bs[16384 + (c*16 + lr)*128 + kidx];
            acc[c] = __builtin_amdgcn_mfma_f32_16x16x32_bf16(ahi, bhi, acc[c], 0, 0, 0);
            acc[c] = __builtin_amdgcn_mfma_f32_16x16x32_bf16(alo, bhi, acc[c], 0, 0, 0);
            acc[c] = __builtin_amdgcn_mfma_f32_16x16x32_bf16(ahi, blo, acc[c], 0, 0, 0);
        }
    }

    float dv[4];
    #pragma unroll
    for(int i = 0; i < 4; ++i){
        int cr = r0 + ((lane >> 4) << 2) + i; if(cr > n-1) cr = n-1;
        dv[i] = dinv[cr];
    }
    #pragma unroll
    for(int c = 0; c < 8; ++c){
        int ccol = c*16 + lr;
        #pragma unroll
        for(int i = 0; i < 4; ++i){
            int crow = r0 + ((lane >> 4) << 2) + i;
            if(crow < n) out[(size_t)crow*128 + ccol] = f2b(acc[c][i] * dv[i]);
        }
    }
}

// ---------------- GEMM (layers 2,3): out_bf16[n,128] = (h_bf16[n,128] @ W) * dinv_row ----------------
// A is bf16 native -> no split, 2 MFMA per fragment (ahi*bhi + ahi*blo).

__global__ __launch_bounds__(256) void gemm_b16A(const unsigned short* __restrict__ in,
                                                 const unsigned short* __restrict__ Wt_hi,
                                                 const unsigned short* __restrict__ Wt_lo,
                                                 const float* __restrict__ dinv,
                                                 unsigned short* __restrict__ out, int n){
    __shared__ __align__(16) unsigned short Bs[32768];
    int t = threadIdx.x;
    int lane = t & 63;
    int r0 = blockIdx.x*64 + (t >> 6)*16;
    int lr = lane & 15;
    int lk = (lane >> 4) * 8;

    {
        uint4* d = (uint4*)Bs;
        const uint4* sH = (const uint4*)Wt_hi;
        const uint4* sL = (const uint4*)Wt_lo;
        #pragma unroll
        for(int i = 0; i < 8; ++i){
            d[t + i*256]        = sH[t + i*256];
            d[2048 + t + i*256] = sL[t + i*256];
        }
    }
    __syncthreads();

    f32x4 acc[8];
    #pragma unroll
    for(int c = 0; c < 8; ++c) acc[c] = (f32x4){0.f, 0.f, 0.f, 0.f};

    int arow_i = r0 + lr; if(arow_i > n-1) arow_i = n-1;
    const unsigned short* arow = in + (size_t)arow_i*128;

    #pragma unroll
    for(int k0 = 0; k0 < 128; k0 += 32){
        bf16x8 ahi = *(const bf16x8*)(arow + k0 + lk);
        int kidx = (k0 + lk) ^ ((lr & 7) << 3);
        #pragma unroll
        for(int c = 0; c < 8; ++c){
            bf16x8 bhi = *(const bf16x8*)&Bs[(c*16 + lr)*128 + kidx];
            bf16x8 blo = *(const bf16x8*)&Bs[16384 + (c*16 + lr)*128 + kidx];
            acc[c] = __builtin_amdgcn_mfma_f32_16x16x32_bf16(ahi, bhi, acc[c], 0, 0, 0);
            acc[c] = __builtin_amdgcn_mfma_f32_16x16x32_bf16(ahi, blo, acc[c], 0, 0, 0);
        }
    }

    float dv[4];
    #pragma unroll
    for(int i = 0; i < 4; ++i){
        int cr = r0 + ((lane >> 4) << 2) + i; if(cr > n-1) cr = n-1;
        dv[i] = dinv[cr];
    }
    #pragma unroll
    for(int c = 0; c < 8; ++c){
        int ccol = c*16 + lr;
        #pragma unroll
        for(int i = 0; i < 4; ++i){
            int crow = r0 + ((lane >> 4) << 2) + i;
            if(crow < n) out[(size_t)crow*128 + ccol] = f2b(acc[c][i] * dv[i]);
        }
    }
}

// ---------------- JK GEMM: out_f32[n,128] = [H0|H1|H2]_bf16[n,384] @ Wjk + bjk ----------------

__global__ __launch_bounds__(256) void gemm_jk(const unsigned short* __restrict__ habc,
                                               const unsigned short* __restrict__ Whi,
                                               const unsigned short* __restrict__ Wlo,
                                               const float* __restrict__ bias,
                                               float* __restrict__ out, int n){
    __shared__ __align__(16) unsigned short Bs[32768];
    int t = threadIdx.x;
    int lane = t & 63;
    int r0 = blockIdx.x*64 + (t >> 6)*16;
    int lr = lane & 15;
    int lk = (lane >> 4) * 8;

    f32x4 acc[8];
    #pragma unroll
    for(int c = 0; c < 8; ++c) acc[c] = (f32x4){0.f, 0.f, 0.f, 0.f};

    int arow_i = r0 + lr; if(arow_i > n-1) arow_i = n-1;

    for(int kb3 = 0; kb3 < 3; ++kb3){
        __syncthreads();
        {
            uint4* d = (uint4*)Bs;
            const uint4* sH = (const uint4*)(Whi + (size_t)(3 + kb3)*16384);
            const uint4* sL = (const uint4*)(Wlo + (size_t)(3 + kb3)*16384);
            #pragma unroll
            for(int i = 0; i < 8; ++i){
                d[t + i*256]        = sH[t + i*256];
                d[2048 + t + i*256] = sL[t + i*256];
            }
        }
        __syncthreads();

        const unsigned short* arow = habc + (size_t)kb3*n*128 + (size_t)arow_i*128;
        #pragma unroll
        for(int k0 = 0; k0 < 128; k0 += 32){
            bf16x8 ahi = *(const bf16x8*)(arow + k0 + lk);
            int kidx = (k0 + lk) ^ ((lr & 7) << 3);
            #pragma unroll
            for(int c = 0; c < 8; ++c){
                bf16x8 bhi = *(const bf16x8*)&Bs[(c*16 + lr)*128 + kidx];
                bf16x8 blo = *(const bf16x8*)&Bs[16384 + (c*16 + lr)*128 + kidx];
                acc[c] = __builtin_amdgcn_mfma_f32_16x16x32_bf16(ahi, bhi, acc[c], 0, 0, 0);
                acc[c] = __builtin_amdgcn_mfma_f32_16x16x32_bf16(ahi, blo, acc[c], 0, 0, 0);
            }
        }
    }

    #pragma unroll
    for(int c = 0; c < 8; ++c){
        int ccol = c*16 + lr;
        float bcol = bias[ccol];
        #pragma unroll
        for(int i = 0; i < 4; ++i){
            int crow = r0 + ((lane >> 4) << 2) + i;
            if(crow < n) out[(size_t)crow*128 + ccol] = acc[c][i] + bcol;
        }
    }
}

// ---------------- pull aggregation (bf16 in/out, f32 accumulate) ----------------
// h[n] = relu(dinv[n]*(y[n] + sum_src y[src]) + b). One node/wave, 256B row gathers,
// 8 independent accumulators. Lane covers features {2*lane, 2*lane+1} via one u32.

__global__ __launch_bounds__(256) void aggregate(const unsigned int* __restrict__ y, const int* __restrict__ row_start,
                                                 const int* __restrict__ csr_src, const float* __restrict__ dinv,
                                                 const float* __restrict__ bias, unsigned int* __restrict__ hout, int n){
    int wave = threadIdx.x >> 6;
    int lane = threadIdx.x & 63;
    int node = blockIdx.x*4 + wave;
    if(node >= n) return;
    int s0 = row_start[node];
    int s1 = row_start[node+1];

    unsigned int self = y[(size_t)node*64 + lane];
    float ax[8], ay[8];
    ax[0] = b2f_lo(self); ay[0] = b2f_hi(self);
    #pragma unroll
    for(int u = 1; u < 8; ++u){ ax[u] = 0.f; ay[u] = 0.f; }

    int j = s0;
    for(; j + 8 <= s1; j += 8){
        int idx[8];
        #pragma unroll
        for(int u = 0; u < 8; ++u) idx[u] = csr_src[j+u];
        #pragma unroll
        for(int u = 0; u < 8; ++u){
            unsigned int v = y[(size_t)idx[u]*64 + lane];
            ax[u] += b2f_lo(v); ay[u] += b2f_hi(v);
        }
    }
    int rem = s1 - j;                      // 0..7 predicated tail
    int idx[7];
    #pragma unroll
    for(int u = 0; u < 7; ++u) idx[u] = (u < rem) ? csr_src[j+u] : node;
    #pragma unroll
    for(int u = 0; u < 7; ++u){
        unsigned int v = y[(size_t)idx[u]*64 + lane];
        if(u < rem){ ax[u] += b2f_lo(v); ay[u] += b2f_hi(v); }
    }

    float s_x = ((ax[0]+ax[1]) + (ax[2]+ax[3])) + ((ax[4]+ax[5]) + (ax[6]+ax[7]));
    float s_y = ((ay[0]+ay[1]) + (ay[2]+ay[3])) + ((ay[4]+ay[5]) + (ay[6]+ay[7]));
    float dn = dinv[node];
    float bx = bias[lane*2], by = bias[lane*2+1];
    float rx = fmaxf(fmaf(s_x, dn, bx), 0.f);
    float ry = fmaxf(fmaf(s_y, dn, by), 0.f);
    unsigned int packed = ((unsigned int)f2b(ry) << 16) | (unsigned int)f2b(rx);
    __builtin_nontemporal_store(packed, &hout[(size_t)node*64 + lane]);
}

// ---------------- pooling over sorted batch (f32 input) ----------------

__global__ void pool_kernel(const float* __restrict__ hjk, const int* __restrict__ batch,
                            int n, float* __restrict__ pooled){
    int c = threadIdx.x;
    int base = blockIdx.x*128;
    int end = base + 128; if(end > n) end = n;
    float acc = 0.f; int cur = -1;
    for(int i = base; i < end; ++i){
        int g = batch[i];
        if(g != cur){
            if(cur >= 0) atomicAdd(&pooled[cur*128 + c], acc);
            cur = g; acc = 0.f;
        }
        acc += hjk[(size_t)i*128 + c];
    }
    if(cur >= 0) atomicAdd(&pooled[cur*128 + c], acc);
}

// ---------------- MLP head ----------------

__global__ void head_kernel(const float* __restrict__ pooled,
                            const float* __restrict__ Wm1, const float* __restrict__ bm1,
                            const float* __restrict__ Wm2, const float* __restrict__ bm2,
                            float* __restrict__ out){
    __shared__ float p[128];
    __shared__ float tq[128];
    int g = blockIdx.x, j = threadIdx.x;
    p[j] = pooled[g*128 + j];
    __syncthreads();
    float a = bm1[j];
    for(int k = 0; k < 128; ++k) a = fmaf(p[k], Wm1[k*128 + j], a);
    tq[j] = fmaxf(a, 0.f);
    __syncthreads();
    if(j < 10){
        float o = bm2[j];
        for(int k = 0; k < 128; ++k) o = fmaf(tq[k], Wm2[k*10 + j], o);
        out[g*10 + j] = o;
    }
}

// ---------------- launch ----------------

extern "C" void kernel_launch(void* const* d_in, const int* in_sizes, int n_in,
                              void* d_out, int out_size, void* d_ws, size_t ws_size,
                              hipStream_t stream){
    const float* x    = (const float*)d_in[0];
    const int*   ei   = (const int*)  d_in[1];
    const int*   batch= (const int*)  d_in[2];
    const float* W0   = (const float*)d_in[3];
    const float* b0   = (const float*)d_in[4];
    const float* W1   = (const float*)d_in[5];
    const float* b1   = (const float*)d_in[6];
    const float* W2   = (const float*)d_in[7];
    const float* b2   = (const float*)d_in[8];
    const float* Wjk  = (const float*)d_in[9];
    const float* bjk  = (const float*)d_in[10];
    const float* Wm1  = (const float*)d_in[11];
    const float* bm1  = (const float*)d_in[12];
    const float* Wm2  = (const float*)d_in[13];
    const float* bm2  = (const float*)d_in[14];

    const int N = in_sizes[0] / 128;
    const int E = in_sizes[1] / 2;
    const int* src = ei;
    const int* dst = ei + E;

    char* ws = (char*)d_ws;
    size_t off = 0;
    auto take = [&](size_t bytes)->char*{
        char* p = ws + off; off = (off + bytes + 255) & ~(size_t)255; return p;
    };
    unsigned short* Y    = (unsigned short*)take((size_t)N*128*2);    // bf16 row-major
    unsigned short* Habc = (unsigned short*)take((size_t)3*N*128*2);  // bf16 [3][N][128]
    float* HJK     = (float*)take((size_t)N*128*4);
    float* dinv    = (float*)take((size_t)N*4);
    int*   deg     = (int*)  take((size_t)N*4);
    int*   cursor  = (int*)  take((size_t)N*4);
    int*   row_start=(int*)  take((size_t)(N+1)*4);
    int*   csr_src = (int*)  take((size_t)E*4 + 64);
    float* pooled  = (float*)take((size_t)512*128*4);
    int*   partials= (int*)  take((size_t)512*4);
    unsigned short* Whi = (unsigned short*)take((size_t)6*16384*2);
    unsigned short* Wlo = (unsigned short*)take((size_t)6*16384*2);

    (void)hipMemsetAsync(deg,    0, (size_t)N*4, stream);
    (void)hipMemsetAsync(pooled, 0, (size_t)512*128*4, stream);

    int nb = (N + 255)/256;
    hist_kernel    <<<(E+255)/256, 256, 0, stream>>>(dst, E, deg);
    scan_part      <<<nb, 256, 0, stream>>>(deg, N, partials);
    scan_partials_k<<<1, 512, 0, stream>>>(partials, nb);
    scan_final     <<<nb, 256, 0, stream>>>(deg, N, partials, row_start, dinv);
    (void)hipMemcpyAsync(cursor, row_start, (size_t)N*4, hipMemcpyDeviceToDevice, stream);
    fill_csr       <<<(E+255)/256, 256, 0, stream>>>(src, dst, E, cursor, csr_src);
    prep_w_all     <<<384, 256, 0, stream>>>(W0, W1, W2, Wjk, Whi, Wlo);

    int gb = (N + 63)/64;
    int ab = (N + 3)/4;
    unsigned short* H0 = Habc;
    unsigned short* H1 = Habc + (size_t)N*128;
    unsigned short* H2 = Habc + (size_t)2*N*128;

    // layer 1 (f32 A)
    gemm_f32A<<<gb, 256, 0, stream>>>(x,  Whi,           Wlo,           dinv, Y, N);
    aggregate<<<ab, 256, 0, stream>>>((const unsigned int*)Y, row_start, csr_src, dinv, b0, (unsigned int*)H0, N);
    // layer 2 (bf16 A)
    gemm_b16A<<<gb, 256, 0, stream>>>(H0, Whi + 1*16384, Wlo + 1*16384, dinv, Y, N);
    aggregate<<<ab, 256, 0, stream>>>((const unsigned int*)Y, row_start, csr_src, dinv, b1, (unsigned int*)H1, N);
    // layer 3 (bf16 A)
    gemm_b16A<<<gb, 256, 0, stream>>>(H1, Whi + 2*16384, Wlo + 2*16384, dinv, Y, N);
    aggregate<<<ab, 256, 0, stream>>>((const unsigned int*)Y, row_start, csr_src, dinv, b2, (unsigned int*)H2, N);
    // JK projection (K=384, bf16 A, 3 staged B-phases)
    gemm_jk<<<gb, 256, 0, stream>>>(Habc, Whi, Wlo, bjk, HJK, N);

    pool_kernel<<<(N+127)/128, 128, 0, stream>>>(HJK, batch, N, pooled);
    head_kernel<<<512, 128, 0, stream>>>(pooled, Wm1, bm1, Wm2, bm2, (float*)d_out);
}

// Round 8
// 547.164 us; speedup vs baseline: 2.9610x; 1.0854x over previous
//
#include <hip/hip_runtime.h>

typedef __attribute__((ext_vector_type(8))) short bf16x8;
typedef __attribute__((ext_vector_type(4))) float f32x4;

#define BSHIFT 11
#define EPT 8
#define CPB 8   // chunks (blocks) per bucket in hist_b/fill_b

__device__ inline unsigned short f2b(float x){
    union{float f; unsigned int u;} c; c.f = x;
    unsigned int r = c.u + 0x7fffu + ((c.u >> 16) & 1u);
    return (unsigned short)(r >> 16);
}
__device__ inline float b2f_lo(unsigned int u){
    union{unsigned int u; float f;} c; c.u = u << 16; return c.f;
}
__device__ inline float b2f_hi(unsigned int u){
    union{unsigned int u; float f;} c; c.u = u & 0xffff0000u; return c.f;
}

// ---------------- bucketed CSR build ----------------
// partition: stream edges, scatter (src,dst) to dst-range buckets (bucket = dst>>11).

__global__ __launch_bounds__(256) void partition_edges(const int* __restrict__ src, const int* __restrict__ dst,
                                                       int E, int* __restrict__ bcursor,
                                                       int2* __restrict__ stage, int cap){
    __shared__ int lcount[64];
    __shared__ int lbase[64];
    int t = threadIdx.x;
    if(t < 64) lcount[t] = 0;
    __syncthreads();
    int e0 = blockIdx.x*256*EPT + t;
    int b[EPT], rank[EPT], s[EPT], d[EPT];
    #pragma unroll
    for(int i = 0; i < EPT; ++i){
        int e = e0 + i*256;
        bool ok = e < E;
        d[i] = ok ? dst[e] : 0;
        s[i] = ok ? src[e] : 0;
        b[i] = d[i] >> BSHIFT;
        rank[i] = ok ? atomicAdd(&lcount[b[i]], 1) : -1;
    }
    __syncthreads();
    if(t < 64){
        int c = lcount[t];
        lbase[t] = (c > 0) ? atomicAdd(&bcursor[t], c) : 0;
    }
    __syncthreads();
    #pragma unroll
    for(int i = 0; i < EPT; ++i){
        if(rank[i] >= 0){
            int pos = lbase[b[i]] + rank[i];
            if(pos < cap) stage[(size_t)b[i]*cap + pos] = make_int2(s[i], d[i]);
        }
    }
}

// hist/fill per bucket; grid laid out so a bucket's blocks share blockIdx%8 (same XCD heuristic).

__global__ __launch_bounds__(256) void hist_b(const int2* __restrict__ stage, const int* __restrict__ bcnt,
                                              int cap, int nb, int* __restrict__ deg){
    int xcd = blockIdx.x & 7, slot = blockIdx.x >> 3;
    int bwx = slot / CPB, chunk = slot - bwx*CPB;
    int b = bwx*8 + xcd;
    if(b >= nb) return;
    int cnt = bcnt[b]; if(cnt > cap) cnt = cap;
    const int2* sp = stage + (size_t)b*cap;
    for(int i = chunk*256 + threadIdx.x; i < cnt; i += CPB*256)
        atomicAdd(&deg[sp[i].y], 1);
}

__global__ __launch_bounds__(256) void fill_b(const int2* __restrict__ stage, const int* __restrict__ bcnt,
                                              int cap, int nb, int* __restrict__ cursor,
                                              int* __restrict__ csr_src){
    int xcd = blockIdx.x & 7, slot = blockIdx.x >> 3;
    int bwx = slot / CPB, chunk = slot - bwx*CPB;
    int b = bwx*8 + xcd;
    if(b >= nb) return;
    int cnt = bcnt[b]; if(cnt > cap) cnt = cap;
    const int2* sp = stage + (size_t)b*cap;
    for(int i = chunk*256 + threadIdx.x; i < cnt; i += CPB*256){
        int2 e = sp[i];
        int p = atomicAdd(&cursor[e.y], 1);
        csr_src[p] = e.x;
    }
}

// ---------------- scans ----------------

__global__ void scan_part(const int* __restrict__ deg, int n, int* __restrict__ partials){
    __shared__ int sm[256];
    int t = threadIdx.x;
    int idx = blockIdx.x*256 + t;
    sm[t] = (idx < n) ? deg[idx] : 0;
    __syncthreads();
    for(int s = 128; s > 0; s >>= 1){ if(t < s) sm[t] += sm[t+s]; __syncthreads(); }
    if(t == 0) partials[blockIdx.x] = sm[0];
}

__global__ void scan_partials_k(int* __restrict__ partials, int nb){
    __shared__ int sm[512];
    int t = threadIdx.x;
    int orig = (t < nb) ? partials[t] : 0;
    sm[t] = orig; __syncthreads();
    for(int s = 1; s < 512; s <<= 1){
        int add = (t >= s) ? sm[t-s] : 0;
        __syncthreads();
        sm[t] += add;
        __syncthreads();
    }
    if(t < nb) partials[t] = sm[t] - orig;   // exclusive
}

__global__ void scan_final(const int* __restrict__ deg, int n,
                           const int* __restrict__ partials, int* __restrict__ row_start,
                           float* __restrict__ dinv){
    __shared__ int sm[256];
    int t = threadIdx.x;
    int idx = blockIdx.x*256 + t;
    int orig = (idx < n) ? deg[idx] : 0;
    sm[t] = orig; __syncthreads();
    for(int s = 1; s < 256; s <<= 1){
        int add = (t >= s) ? sm[t-s] : 0;
        __syncthreads();
        sm[t] += add;
        __syncthreads();
    }
    int excl = partials[blockIdx.x] + sm[t] - orig;
    if(idx < n){
        row_start[idx] = excl;
        dinv[idx] = rsqrtf((float)orig + 1.0f);
    }
    if(idx == n-1) row_start[n] = excl + orig;   // == E
}

// ---------------- weight prep: f32 -> transposed, XOR-swizzled bf16 hi/lo ----------------

__device__ inline void split_bf16(float x, unsigned short& h, unsigned short& l){
    union { float f; unsigned int u; } cv;
    cv.f = x;
    unsigned int u = cv.u;
    unsigned int rh = u + 0x7fffu + ((u >> 16) & 1u);
    h = (unsigned short)(rh >> 16);
    union { unsigned int u; float f; } hb;
    hb.u = ((unsigned int)h) << 16;
    float r = x - hb.f;
    cv.f = r;
    unsigned int u2 = cv.u;
    unsigned int rl = u2 + 0x7fffu + ((u2 >> 16) & 1u);
    l = (unsigned short)(rl >> 16);
}

__global__ void prep_w_all(const float* __restrict__ W0, const float* __restrict__ W1,
                           const float* __restrict__ W2, const float* __restrict__ Wjk,
                           unsigned short* __restrict__ hi, unsigned short* __restrict__ lo){
    int m = blockIdx.x >> 6;                         // 0..5
    int i = (blockIdx.x & 63)*256 + threadIdx.x;     // 0..16383
    const float* W = (m==0) ? W0 : (m==1) ? W1 : (m==2) ? W2 : (Wjk + (m-3)*16384);
    int k = i >> 7, c = i & 127;                     // W is [k][c]
    unsigned short h, l;
    split_bf16(W[i], h, l);
    size_t o = (size_t)m*16384 + c*128 + (k ^ ((c & 7) << 3));
    hi[o] = h;
    lo[o] = l;
}

// ---------------- GEMM (layer 1): out_bf16 = (x_f32 @ W) * dinv_row ----------------

__global__ __launch_bounds__(256) void gemm_f32A(const float* __restrict__ in,
                                                 const unsigned short* __restrict__ Wt_hi,
                                                 const unsigned short* __restrict__ Wt_lo,
                                                 const float* __restrict__ dinv,
                                                 unsigned short* __restrict__ out, int n){
    __shared__ __align__(16) unsigned short Bs[32768];
    int t = threadIdx.x;
    int lane = t & 63;
    int r0 = blockIdx.x*64 + (t >> 6)*16;
    int lr = lane & 15;
    int lk = (lane >> 4) * 8;

    {
        uint4* d = (uint4*)Bs;
        const uint4* sH = (const uint4*)Wt_hi;
        const uint4* sL = (const uint4*)Wt_lo;
        #pragma unroll
        for(int i = 0; i < 8; ++i){
            d[t + i*256]        = sH[t + i*256];
            d[2048 + t + i*256] = sL[t + i*256];
        }
    }
    __syncthreads();

    f32x4 acc[8];
    #pragma unroll
    for(int c = 0; c < 8; ++c) acc[c] = (f32x4){0.f, 0.f, 0.f, 0.f};

    int arow_i = r0 + lr; if(arow_i > n-1) arow_i = n-1;
    const float* arow = in + (size_t)arow_i*128;

    #pragma unroll
    for(int k0 = 0; k0 < 128; k0 += 32){
        f32x4 a0 = *(const f32x4*)(arow + k0 + lk);
        f32x4 a1 = *(const f32x4*)(arow + k0 + lk + 4);
        bf16x8 ahi, alo;
        #pragma unroll
        for(int j = 0; j < 4; ++j){
            unsigned short h, l;
            split_bf16(a0[j], h, l);
            ahi[j] = (short)h; alo[j] = (short)l;
            split_bf16(a1[j], h, l);
            ahi[j+4] = (short)h; alo[j+4] = (short)l;
        }
        int kidx = (k0 + lk) ^ ((lr & 7) << 3);
        #pragma unroll
        for(int c = 0; c < 8; ++c){
            bf16x8 bhi = *(const bf16x8*)&Bs[(c*16 + lr)*128 + kidx];
            bf16x8 blo = *(const bf16x8*)&Bs[16384 + (c*16 + lr)*128 + kidx];
            acc[c] = __builtin_amdgcn_mfma_f32_16x16x32_bf16(ahi, bhi, acc[c], 0, 0, 0);
            acc[c] = __builtin_amdgcn_mfma_f32_16x16x32_bf16(alo, bhi, acc[c], 0, 0, 0);
            acc[c] = __builtin_amdgcn_mfma_f32_16x16x32_bf16(ahi, blo, acc[c], 0, 0, 0);
        }
    }

    float dv[4];
    #pragma unroll
    for(int i = 0; i < 4; ++i){
        int cr = r0 + ((lane >> 4) << 2) + i; if(cr > n-1) cr = n-1;
        dv[i] = dinv[cr];
    }
    #pragma unroll
    for(int c = 0; c < 8; ++c){
        int ccol = c*16 + lr;
        #pragma unroll
        for(int i = 0; i < 4; ++i){
            int crow = r0 + ((lane >> 4) << 2) + i;
            if(crow < n) out[(size_t)crow*128 + ccol] = f2b(acc[c][i] * dv[i]);
        }
    }
}

// ---------------- GEMM (layers 2,3): bf16 A native, 2 MFMA/frag ----------------

__global__ __launch_bounds__(256) void gemm_b16A(const unsigned short* __restrict__ in,
                                                 const unsigned short* __restrict__ Wt_hi,
                                                 const unsigned short* __restrict__ Wt_lo,
                                                 const float* __restrict__ dinv,
                                                 unsigned short* __restrict__ out, int n){
    __shared__ __align__(16) unsigned short Bs[32768];
    int t = threadIdx.x;
    int lane = t & 63;
    int r0 = blockIdx.x*64 + (t >> 6)*16;
    int lr = lane & 15;
    int lk = (lane >> 4) * 8;

    {
        uint4* d = (uint4*)Bs;
        const uint4* sH = (const uint4*)Wt_hi;
        const uint4* sL = (const uint4*)Wt_lo;
        #pragma unroll
        for(int i = 0; i < 8; ++i){
            d[t + i*256]        = sH[t + i*256];
            d[2048 + t + i*256] = sL[t + i*256];
        }
    }
    __syncthreads();

    f32x4 acc[8];
    #pragma unroll
    for(int c = 0; c < 8; ++c) acc[c] = (f32x4){0.f, 0.f, 0.f, 0.f};

    int arow_i = r0 + lr; if(arow_i > n-1) arow_i = n-1;
    const unsigned short* arow = in + (size_t)arow_i*128;

    #pragma unroll
    for(int k0 = 0; k0 < 128; k0 += 32){
        bf16x8 ahi = *(const bf16x8*)(arow + k0 + lk);
        int kidx = (k0 + lk) ^ ((lr & 7) << 3);
        #pragma unroll
        for(int c = 0; c < 8; ++c){
            bf16x8 bhi = *(const bf16x8*)&Bs[(c*16 + lr)*128 + kidx];
            bf16x8 blo = *(const bf16x8*)&Bs[16384 + (c*16 + lr)*128 + kidx];
            acc[c] = __builtin_amdgcn_mfma_f32_16x16x32_bf16(ahi, bhi, acc[c], 0, 0, 0);
            acc[c] = __builtin_amdgcn_mfma_f32_16x16x32_bf16(ahi, blo, acc[c], 0, 0, 0);
        }
    }

    float dv[4];
    #pragma unroll
    for(int i = 0; i < 4; ++i){
        int cr = r0 + ((lane >> 4) << 2) + i; if(cr > n-1) cr = n-1;
        dv[i] = dinv[cr];
    }
    #pragma unroll
    for(int c = 0; c < 8; ++c){
        int ccol = c*16 + lr;
        #pragma unroll
        for(int i = 0; i < 4; ++i){
            int crow = r0 + ((lane >> 4) << 2) + i;
            if(crow < n) out[(size_t)crow*128 + ccol] = f2b(acc[c][i] * dv[i]);
        }
    }
}

// ---------------- JK GEMM: out_f32[n,128] = [H0|H1|H2]_bf16[n,384] @ Wjk + bjk ----------------

__global__ __launch_bounds__(256) void gemm_jk(const unsigned short* __restrict__ habc,
                                               const unsigned short* __restrict__ Whi,
                                               const unsigned short* __restrict__ Wlo,
                                               const float* __restrict__ bias,
                                               float* __restrict__ out, int n){
    __shared__ __align__(16) unsigned short Bs[32768];
    int t = threadIdx.x;
    int lane = t & 63;
    int r0 = blockIdx.x*64 + (t >> 6)*16;
    int lr = lane & 15;
    int lk = (lane >> 4) * 8;

    f32x4 acc[8];
    #pragma unroll
    for(int c = 0; c < 8; ++c) acc[c] = (f32x4){0.f, 0.f, 0.f, 0.f};

    int arow_i = r0 + lr; if(arow_i > n-1) arow_i = n-1;

    for(int kb3 = 0; kb3 < 3; ++kb3){
        __syncthreads();
        {
            uint4* d = (uint4*)Bs;
            const uint4* sH = (const uint4*)(Whi + (size_t)(3 + kb3)*16384);
            const uint4* sL = (const uint4*)(Wlo + (size_t)(3 + kb3)*16384);
            #pragma unroll
            for(int i = 0; i < 8; ++i){
                d[t + i*256]        = sH[t + i*256];
                d[2048 + t + i*256] = sL[t + i*256];
            }
        }
        __syncthreads();

        const unsigned short* arow = habc + (size_t)kb3*n*128 + (size_t)arow_i*128;
        #pragma unroll
        for(int k0 = 0; k0 < 128; k0 += 32){
            bf16x8 ahi = *(const bf16x8*)(arow + k0 + lk);
            int kidx = (k0 + lk) ^ ((lr & 7) << 3);
            #pragma unroll
            for(int c = 0; c < 8; ++c){
                bf16x8 bhi = *(const bf16x8*)&Bs[(c*16 + lr)*128 + kidx];
                bf16x8 blo = *(const bf16x8*)&Bs[16384 + (c*16 + lr)*128 + kidx];
                acc[c] = __builtin_amdgcn_mfma_f32_16x16x32_bf16(ahi, bhi, acc[c], 0, 0, 0);
                acc[c] = __builtin_amdgcn_mfma_f32_16x16x32_bf16(ahi, blo, acc[c], 0, 0, 0);
            }
        }
    }

    #pragma unroll
    for(int c = 0; c < 8; ++c){
        int ccol = c*16 + lr;
        float bcol = bias[ccol];
        #pragma unroll
        for(int i = 0; i < 4; ++i){
            int crow = r0 + ((lane >> 4) << 2) + i;
            if(crow < n) out[(size_t)crow*128 + ccol] = acc[c][i] + bcol;
        }
    }
}

// ---------------- pull aggregation (bf16 in/out, f32 accumulate) ----------------

__global__ __launch_bounds__(256) void aggregate(const unsigned int* __restrict__ y, const int* __restrict__ row_start,
                                                 const int* __restrict__ csr_src, const float* __restrict__ dinv,
                                                 const float* __restrict__ bias, unsigned int* __restrict__ hout, int n){
    int wave = threadIdx.x >> 6;
    int lane = threadIdx.x & 63;
    int node = blockIdx.x*4 + wave;
    if(node >= n) return;
    int s0 = row_start[node];
    int s1 = row_start[node+1];

    unsigned int self = y[(size_t)node*64 + lane];
    float ax[8], ay[8];
    ax[0] = b2f_lo(self); ay[0] = b2f_hi(self);
    #pragma unroll
    for(int u = 1; u < 8; ++u){ ax[u] = 0.f; ay[u] = 0.f; }

    int j = s0;
    for(; j + 8 <= s1; j += 8){
        int idx[8];
        #pragma unroll
        for(int u = 0; u < 8; ++u) idx[u] = csr_src[j+u];
        #pragma unroll
        for(int u = 0; u < 8; ++u){
            unsigned int v = y[(size_t)idx[u]*64 + lane];
            ax[u] += b2f_lo(v); ay[u] += b2f_hi(v);
        }
    }
    int rem = s1 - j;
    int idx[7];
    #pragma unroll
    for(int u = 0; u < 7; ++u) idx[u] = (u < rem) ? csr_src[j+u] : node;
    #pragma unroll
    for(int u = 0; u < 7; ++u){
        unsigned int v = y[(size_t)idx[u]*64 + lane];
        if(u < rem){ ax[u] += b2f_lo(v); ay[u] += b2f_hi(v); }
    }

    float s_x = ((ax[0]+ax[1]) + (ax[2]+ax[3])) + ((ax[4]+ax[5]) + (ax[6]+ax[7]));
    float s_y = ((ay[0]+ay[1]) + (ay[2]+ay[3])) + ((ay[4]+ay[5]) + (ay[6]+ay[7]));
    float dn = dinv[node];
    float bx = bias[lane*2], by = bias[lane*2+1];
    float rx = fmaxf(fmaf(s_x, dn, bx), 0.f);
    float ry = fmaxf(fmaf(s_y, dn, by), 0.f);
    unsigned int packed = ((unsigned int)f2b(ry) << 16) | (unsigned int)f2b(rx);
    __builtin_nontemporal_store(packed, &hout[(size_t)node*64 + lane]);
}

// ---------------- pooling over sorted batch ----------------

__global__ void pool_kernel(const float* __restrict__ hjk, const int* __restrict__ batch,
                            int n, float* __restrict__ pooled){
    int c = threadIdx.x;
    int base = blockIdx.x*128;
    int end = base + 128; if(end > n) end = n;
    float acc = 0.f; int cur = -1;
    for(int i = base; i < end; ++i){
        int g = batch[i];
        if(g != cur){
            if(cur >= 0) atomicAdd(&pooled[cur*128 + c], acc);
            cur = g; acc = 0.f;
        }
        acc += hjk[(size_t)i*128 + c];
    }
    if(cur >= 0) atomicAdd(&pooled[cur*128 + c], acc);
}

// ---------------- MLP head ----------------

__global__ void head_kernel(const float* __restrict__ pooled,
                            const float* __restrict__ Wm1, const float* __restrict__ bm1,
                            const float* __restrict__ Wm2, const float* __restrict__ bm2,
                            float* __restrict__ out){
    __shared__ float p[128];
    __shared__ float tq[128];
    int g = blockIdx.x, j = threadIdx.x;
    p[j] = pooled[g*128 + j];
    __syncthreads();
    float a = bm1[j];
    for(int k = 0; k < 128; ++k) a = fmaf(p[k], Wm1[k*128 + j], a);
    tq[j] = fmaxf(a, 0.f);
    __syncthreads();
    if(j < 10){
        float o = bm2[j];
        for(int k = 0; k < 128; ++k) o = fmaf(tq[k], Wm2[k*10 + j], o);
        out[g*10 + j] = o;
    }
}

// ---------------- launch ----------------

extern "C" void kernel_launch(void* const* d_in, const int* in_sizes, int n_in,
                              void* d_out, int out_size, void* d_ws, size_t ws_size,
                              hipStream_t stream){
    const float* x    = (const float*)d_in[0];
    const int*   ei   = (const int*)  d_in[1];
    const int*   batch= (const int*)  d_in[2];
    const float* W0   = (const float*)d_in[3];
    const float* b0   = (const float*)d_in[4];
    const float* W1   = (const float*)d_in[5];
    const float* b1   = (const float*)d_in[6];
    const float* W2   = (const float*)d_in[7];
    const float* b2   = (const float*)d_in[8];
    const float* Wjk  = (const float*)d_in[9];
    const float* bjk  = (const float*)d_in[10];
    const float* Wm1  = (const float*)d_in[11];
    const float* bm1  = (const float*)d_in[12];
    const float* Wm2  = (const float*)d_in[13];
    const float* bm2  = (const float*)d_in[14];

    const int N = in_sizes[0] / 128;
    const int E = in_sizes[1] / 2;
    const int* src = ei;
    const int* dst = ei + E;

    const int nbuck = (N + (1<<BSHIFT) - 1) >> BSHIFT;            // 49 for N=100k
    const int cap   = E/nbuck + E/(nbuck*4) + 2048;               // mean + 25% + slack

    char* ws = (char*)d_ws;
    size_t off = 0;
    auto take = [&](size_t bytes)->char*{
        char* p = ws + off; off = (off + bytes + 255) & ~(size_t)255; return p;
    };
    unsigned short* Y    = (unsigned short*)take((size_t)N*128*2);    // bf16 row-major
    unsigned short* Habc = (unsigned short*)take((size_t)3*N*128*2);  // bf16 [3][N][128]
    float* HJK     = (float*)take((size_t)N*128*4);
    float* dinv    = (float*)take((size_t)N*4);
    int*   deg     = (int*)  take((size_t)N*4);
    int*   cursor  = (int*)  take((size_t)N*4);
    int*   row_start=(int*)  take((size_t)(N+1)*4);
    int*   csr_src = (int*)  take((size_t)E*4 + 64);
    float* pooled  = (float*)take((size_t)512*128*4);
    int*   partials= (int*)  take((size_t)512*4);
    unsigned short* Whi = (unsigned short*)take((size_t)6*16384*2);
    unsigned short* Wlo = (unsigned short*)take((size_t)6*16384*2);
    int*   bcursor = (int*)  take((size_t)64*4);
    int2*  stage   = (int2*) take((size_t)nbuck*cap*8);

    (void)hipMemsetAsync(deg,     0, (size_t)N*4, stream);
    (void)hipMemsetAsync(pooled,  0, (size_t)512*128*4, stream);
    (void)hipMemsetAsync(bcursor, 0, (size_t)64*4, stream);

    int nb = (N + 255)/256;
    int bgrid = 8 * ((nbuck + 7)/8) * CPB;

    partition_edges<<<(E + 256*EPT - 1)/(256*EPT), 256, 0, stream>>>(src, dst, E, bcursor, stage, cap);
    hist_b         <<<bgrid, 256, 0, stream>>>(stage, bcursor, cap, nbuck, deg);
    scan_part      <<<nb, 256, 0, stream>>>(deg, N, partials);
    scan_partials_k<<<1, 512, 0, stream>>>(partials, nb);
    scan_final     <<<nb, 256, 0, stream>>>(deg, N, partials, row_start, dinv);
    (void)hipMemcpyAsync(cursor, row_start, (size_t)N*4, hipMemcpyDeviceToDevice, stream);
    fill_b         <<<bgrid, 256, 0, stream>>>(stage, bcursor, cap, nbuck, cursor, csr_src);
    prep_w_all     <<<384, 256, 0, stream>>>(W0, W1, W2, Wjk, Whi, Wlo);

    int gb = (N + 63)/64;
    int ab = (N + 3)/4;
    unsigned short* H0 = Habc;
    unsigned short* H1 = Habc + (size_t)N*128;
    unsigned short* H2 = Habc + (size_t)2*N*128;

    // layer 1 (f32 A)
    gemm_f32A<<<gb, 256, 0, stream>>>(x,  Whi,           Wlo,           dinv, Y, N);
    aggregate<<<ab, 256, 0, stream>>>((const unsigned int*)Y, row_start, csr_src, dinv, b0, (unsigned int*)H0, N);
    // layer 2 (bf16 A)
    gemm_b16A<<<gb, 256, 0, stream>>>(H0, Whi + 1*16384, Wlo + 1*16384, dinv, Y, N);
    aggregate<<<ab, 256, 0, stream>>>((const unsigned int*)Y, row_start, csr_src, dinv, b1, (unsigned int*)H1, N);
    // layer 3 (bf16 A)
    gemm_b16A<<<gb, 256, 0, stream>>>(H1, Whi + 2*16384, Wlo + 2*16384, dinv, Y, N);
    aggregate<<<ab, 256, 0, stream>>>((const unsigned int*)Y, row_start, csr_src, dinv, b2, (unsigned int*)H2, N);
    // JK projection (K=384, bf16 A, 3 staged B-phases)
    gemm_jk<<<gb, 256, 0, stream>>>(Habc, Whi, Wlo, bjk, HJK, N);

    pool_kernel<<<(N+127)/128, 128, 0, stream>>>(HJK, batch, N, pooled);
    head_kernel<<<512, 128, 0, stream>>>(pooled, Wm1, bm1, Wm2, bm2, (float*)d_out);
}

// Round 9
// 488.923 us; speedup vs baseline: 3.3137x; 1.1191x over previous
//
#include <hip/hip_runtime.h>

typedef __attribute__((ext_vector_type(8))) short bf16x8;
typedef __attribute__((ext_vector_type(4))) float f32x4;

#define BSHIFT 11
#define EPT 8
#define CPB 16   // chunks (blocks) per bucket in hist_b/fill_b

__device__ inline unsigned short f2b(float x){
    union{float f; unsigned int u;} c; c.f = x;
    unsigned int r = c.u + 0x7fffu + ((c.u >> 16) & 1u);
    return (unsigned short)(r >> 16);
}
__device__ inline float b2f_lo(unsigned int u){
    union{unsigned int u; float f;} c; c.u = u << 16; return c.f;
}
__device__ inline float b2f_hi(unsigned int u){
    union{unsigned int u; float f;} c; c.u = u & 0xffff0000u; return c.f;
}

// ---------------- bucketed CSR build ----------------
// partition: stream edges, scatter packed (src<<11 | dst&2047) to dst-range buckets.

__global__ __launch_bounds__(256) void partition_edges(const int* __restrict__ src, const int* __restrict__ dst,
                                                       int E, int* __restrict__ bcursor,
                                                       int* __restrict__ stage, int cap){
    __shared__ int lcount[64];
    __shared__ int lbase[64];
    int t = threadIdx.x;
    if(t < 64) lcount[t] = 0;
    __syncthreads();
    int e0 = blockIdx.x*256*EPT + t;
    int b[EPT], rank[EPT], v[EPT];
    #pragma unroll
    for(int i = 0; i < EPT; ++i){
        int e = e0 + i*256;
        bool ok = e < E;
        int d = ok ? dst[e] : 0;
        int s = ok ? src[e] : 0;
        b[i] = d >> BSHIFT;
        v[i] = (s << BSHIFT) | (d & ((1<<BSHIFT)-1));
        rank[i] = ok ? atomicAdd(&lcount[b[i]], 1) : -1;
    }
    __syncthreads();
    if(t < 64){
        int c = lcount[t];
        lbase[t] = (c > 0) ? atomicAdd(&bcursor[t], c) : 0;
    }
    __syncthreads();
    #pragma unroll
    for(int i = 0; i < EPT; ++i){
        if(rank[i] >= 0){
            int pos = lbase[b[i]] + rank[i];
            if(pos < cap) stage[(size_t)b[i]*cap + pos] = v[i];
        }
    }
}

// hist/fill per bucket; grid laid out so a bucket's blocks share blockIdx%8 (same XCD heuristic).

__global__ __launch_bounds__(256) void hist_b(const int* __restrict__ stage, const int* __restrict__ bcnt,
                                              int cap, int nb, int* __restrict__ deg){
    int xcd = blockIdx.x & 7, slot = blockIdx.x >> 3;
    int bwx = slot / CPB, chunk = slot - bwx*CPB;
    int b = bwx*8 + xcd;
    if(b >= nb) return;
    int cnt = bcnt[b]; if(cnt > cap) cnt = cap;
    int dbase = b << BSHIFT;
    const int* sp = stage + (size_t)b*cap;
    for(int i = chunk*256 + threadIdx.x; i < cnt; i += CPB*256){
        int v = sp[i];
        atomicAdd(&deg[dbase + (v & ((1<<BSHIFT)-1))], 1);
    }
}

__global__ __launch_bounds__(256) void fill_b(const int* __restrict__ stage, const int* __restrict__ bcnt,
                                              int cap, int nb, int* __restrict__ cursor,
                                              int* __restrict__ csr_src){
    int xcd = blockIdx.x & 7, slot = blockIdx.x >> 3;
    int bwx = slot / CPB, chunk = slot - bwx*CPB;
    int b = bwx*8 + xcd;
    if(b >= nb) return;
    int cnt = bcnt[b]; if(cnt > cap) cnt = cap;
    int dbase = b << BSHIFT;
    const int* sp = stage + (size_t)b*cap;
    for(int i = chunk*256 + threadIdx.x; i < cnt; i += CPB*256){
        int v = sp[i];
        int p = atomicAdd(&cursor[dbase + (v & ((1<<BSHIFT)-1))], 1);
        csr_src[p] = v >> BSHIFT;
    }
}

// ---------------- scans ----------------

__global__ void scan_part(const int* __restrict__ deg, int n, int* __restrict__ partials){
    __shared__ int sm[256];
    int t = threadIdx.x;
    int idx = blockIdx.x*256 + t;
    sm[t] = (idx < n) ? deg[idx] : 0;
    __syncthreads();
    for(int s = 128; s > 0; s >>= 1){ if(t < s) sm[t] += sm[t+s]; __syncthreads(); }
    if(t == 0) partials[blockIdx.x] = sm[0];
}

__global__ void scan_partials_k(int* __restrict__ partials, int nb){
    __shared__ int sm[512];
    int t = threadIdx.x;
    int orig = (t < nb) ? partials[t] : 0;
    sm[t] = orig; __syncthreads();
    for(int s = 1; s < 512; s <<= 1){
        int add = (t >= s) ? sm[t-s] : 0;
        __syncthreads();
        sm[t] += add;
        __syncthreads();
    }
    if(t < nb) partials[t] = sm[t] - orig;   // exclusive
}

__global__ void scan_final(const int* __restrict__ deg, int n,
                           const int* __restrict__ partials, int* __restrict__ row_start,
                           float* __restrict__ dinv){
    __shared__ int sm[256];
    int t = threadIdx.x;
    int idx = blockIdx.x*256 + t;
    int orig = (idx < n) ? deg[idx] : 0;
    sm[t] = orig; __syncthreads();
    for(int s = 1; s < 256; s <<= 1){
        int add = (t >= s) ? sm[t-s] : 0;
        __syncthreads();
        sm[t] += add;
        __syncthreads();
    }
    int excl = partials[blockIdx.x] + sm[t] - orig;
    if(idx < n){
        row_start[idx] = excl;
        dinv[idx] = rsqrtf((float)orig + 1.0f);
    }
    if(idx == n-1) row_start[n] = excl + orig;   // == E
}

// ---------------- weight prep: f32 -> transposed, XOR-swizzled bf16 hi/lo ----------------

__device__ inline void split_bf16(float x, unsigned short& h, unsigned short& l){
    union { float f; unsigned int u; } cv;
    cv.f = x;
    unsigned int u = cv.u;
    unsigned int rh = u + 0x7fffu + ((u >> 16) & 1u);
    h = (unsigned short)(rh >> 16);
    union { unsigned int u; float f; } hb;
    hb.u = ((unsigned int)h) << 16;
    float r = x - hb.f;
    cv.f = r;
    unsigned int u2 = cv.u;
    unsigned int rl = u2 + 0x7fffu + ((u2 >> 16) & 1u);
    l = (unsigned short)(rl >> 16);
}

__global__ void prep_w_all(const float* __restrict__ W0, const float* __restrict__ W1,
                           const float* __restrict__ W2, const float* __restrict__ Wjk,
                           unsigned short* __restrict__ hi, unsigned short* __restrict__ lo){
    int m = blockIdx.x >> 6;                         // 0..5
    int i = (blockIdx.x & 63)*256 + threadIdx.x;     // 0..16383
    const float* W = (m==0) ? W0 : (m==1) ? W1 : (m==2) ? W2 : (Wjk + (m-3)*16384);
    int k = i >> 7, c = i & 127;                     // W is [k][c]
    unsigned short h, l;
    split_bf16(W[i], h, l);
    size_t o = (size_t)m*16384 + c*128 + (k ^ ((c & 7) << 3));
    hi[o] = h;
    lo[o] = l;
}

// ---------------- GEMM (layer 1): out_bf16 = (x_f32 @ W) * dinv_row ----------------
// 512 threads (8 waves) share one 64KB LDS B-stage -> 4 waves/SIMD.

__global__ __launch_bounds__(512) void gemm_f32A(const float* __restrict__ in,
                                                 const unsigned short* __restrict__ Wt_hi,
                                                 const unsigned short* __restrict__ Wt_lo,
                                                 const float* __restrict__ dinv,
                                                 unsigned short* __restrict__ out, int n){
    __shared__ __align__(16) unsigned short Bs[32768];
    int t = threadIdx.x;
    int lane = t & 63;
    int r0 = blockIdx.x*128 + (t >> 6)*16;
    int lr = lane & 15;
    int lk = (lane >> 4) * 8;

    {
        uint4* d = (uint4*)Bs;
        const uint4* sH = (const uint4*)Wt_hi;
        const uint4* sL = (const uint4*)Wt_lo;
        #pragma unroll
        for(int i = 0; i < 4; ++i){
            d[t + i*512]        = sH[t + i*512];
            d[2048 + t + i*512] = sL[t + i*512];
        }
    }
    __syncthreads();

    f32x4 acc[8];
    #pragma unroll
    for(int c = 0; c < 8; ++c) acc[c] = (f32x4){0.f, 0.f, 0.f, 0.f};

    int arow_i = r0 + lr; if(arow_i > n-1) arow_i = n-1;
    const float* arow = in + (size_t)arow_i*128;

    #pragma unroll
    for(int k0 = 0; k0 < 128; k0 += 32){
        f32x4 a0 = *(const f32x4*)(arow + k0 + lk);
        f32x4 a1 = *(const f32x4*)(arow + k0 + lk + 4);
        bf16x8 ahi, alo;
        #pragma unroll
        for(int j = 0; j < 4; ++j){
            unsigned short h, l;
            split_bf16(a0[j], h, l);
            ahi[j] = (short)h; alo[j] = (short)l;
            split_bf16(a1[j], h, l);
            ahi[j+4] = (short)h; alo[j+4] = (short)l;
        }
        int kidx = (k0 + lk) ^ ((lr & 7) << 3);
        #pragma unroll
        for(int c = 0; c < 8; ++c){
            bf16x8 bhi = *(const bf16x8*)&Bs[(c*16 + lr)*128 + kidx];
            bf16x8 blo = *(const bf16x8*)&Bs[16384 + (c*16 + lr)*128 + kidx];
            acc[c] = __builtin_amdgcn_mfma_f32_16x16x32_bf16(ahi, bhi, acc[c], 0, 0, 0);
            acc[c] = __builtin_amdgcn_mfma_f32_16x16x32_bf16(alo, bhi, acc[c], 0, 0, 0);
            acc[c] = __builtin_amdgcn_mfma_f32_16x16x32_bf16(ahi, blo, acc[c], 0, 0, 0);
        }
    }

    float dv[4];
    #pragma unroll
    for(int i = 0; i < 4; ++i){
        int cr = r0 + ((lane >> 4) << 2) + i; if(cr > n-1) cr = n-1;
        dv[i] = dinv[cr];
    }
    #pragma unroll
    for(int c = 0; c < 8; ++c){
        int ccol = c*16 + lr;
        #pragma unroll
        for(int i = 0; i < 4; ++i){
            int crow = r0 + ((lane >> 4) << 2) + i;
            if(crow < n) out[(size_t)crow*128 + ccol] = f2b(acc[c][i] * dv[i]);
        }
    }
}

// ---------------- GEMM (layers 2,3): bf16 A native, 2 MFMA/frag, 512 threads ----------------

__global__ __launch_bounds__(512) void gemm_b16A(const unsigned short* __restrict__ in,
                                                 const unsigned short* __restrict__ Wt_hi,
                                                 const unsigned short* __restrict__ Wt_lo,
                                                 const float* __restrict__ dinv,
                                                 unsigned short* __restrict__ out, int n){
    __shared__ __align__(16) unsigned short Bs[32768];
    int t = threadIdx.x;
    int lane = t & 63;
    int r0 = blockIdx.x*128 + (t >> 6)*16;
    int lr = lane & 15;
    int lk = (lane >> 4) * 8;

    {
        uint4* d = (uint4*)Bs;
        const uint4* sH = (const uint4*)Wt_hi;
        const uint4* sL = (const uint4*)Wt_lo;
        #pragma unroll
        for(int i = 0; i < 4; ++i){
            d[t + i*512]        = sH[t + i*512];
            d[2048 + t + i*512] = sL[t + i*512];
        }
    }
    __syncthreads();

    f32x4 acc[8];
    #pragma unroll
    for(int c = 0; c < 8; ++c) acc[c] = (f32x4){0.f, 0.f, 0.f, 0.f};

    int arow_i = r0 + lr; if(arow_i > n-1) arow_i = n-1;
    const unsigned short* arow = in + (size_t)arow_i*128;

    #pragma unroll
    for(int k0 = 0; k0 < 128; k0 += 32){
        bf16x8 ahi = *(const bf16x8*)(arow + k0 + lk);
        int kidx = (k0 + lk) ^ ((lr & 7) << 3);
        #pragma unroll
        for(int c = 0; c < 8; ++c){
            bf16x8 bhi = *(const bf16x8*)&Bs[(c*16 + lr)*128 + kidx];
            bf16x8 blo = *(const bf16x8*)&Bs[16384 + (c*16 + lr)*128 + kidx];
            acc[c] = __builtin_amdgcn_mfma_f32_16x16x32_bf16(ahi, bhi, acc[c], 0, 0, 0);
            acc[c] = __builtin_amdgcn_mfma_f32_16x16x32_bf16(ahi, blo, acc[c], 0, 0, 0);
        }
    }

    float dv[4];
    #pragma unroll
    for(int i = 0; i < 4; ++i){
        int cr = r0 + ((lane >> 4) << 2) + i; if(cr > n-1) cr = n-1;
        dv[i] = dinv[cr];
    }
    #pragma unroll
    for(int c = 0; c < 8; ++c){
        int ccol = c*16 + lr;
        #pragma unroll
        for(int i = 0; i < 4; ++i){
            int crow = r0 + ((lane >> 4) << 2) + i;
            if(crow < n) out[(size_t)crow*128 + ccol] = f2b(acc[c][i] * dv[i]);
        }
    }
}

// ---------------- JK GEMM + fused pooling ----------------
// pooled[g] += sum over rows of (concat(H)[row] @ Wjk + bjk); batch sorted -> wave-uniform
// fast path (in-wave row reduce + 128 atomics/wave), per-row atomic fallback at boundaries.

__global__ __launch_bounds__(512) void gemm_jk_pool(const unsigned short* __restrict__ habc,
                                                    const unsigned short* __restrict__ Whi,
                                                    const unsigned short* __restrict__ Wlo,
                                                    const float* __restrict__ bias,
                                                    const int* __restrict__ batch,
                                                    float* __restrict__ pooled, int n){
    __shared__ __align__(16) unsigned short Bs[32768];
    int t = threadIdx.x;
    int lane = t & 63;
    int r0 = blockIdx.x*128 + (t >> 6)*16;
    int lr = lane & 15;
    int lk = (lane >> 4) * 8;

    f32x4 acc[8];
    #pragma unroll
    for(int c = 0; c < 8; ++c) acc[c] = (f32x4){0.f, 0.f, 0.f, 0.f};

    int arow_i = r0 + lr; if(arow_i > n-1) arow_i = n-1;

    for(int kb3 = 0; kb3 < 3; ++kb3){
        __syncthreads();
        {
            uint4* d = (uint4*)Bs;
            const uint4* sH = (const uint4*)(Whi + (size_t)(3 + kb3)*16384);
            const uint4* sL = (const uint4*)(Wlo + (size_t)(3 + kb3)*16384);
            #pragma unroll
            for(int i = 0; i < 4; ++i){
                d[t + i*512]        = sH[t + i*512];
                d[2048 + t + i*512] = sL[t + i*512];
            }
        }
        __syncthreads();

        const unsigned short* arow = habc + (size_t)kb3*n*128 + (size_t)arow_i*128;
        #pragma unroll
        for(int k0 = 0; k0 < 128; k0 += 32){
            bf16x8 ahi = *(const bf16x8*)(arow + k0 + lk);
            int kidx = (k0 + lk) ^ ((lr & 7) << 3);
            #pragma unroll
            for(int c = 0; c < 8; ++c){
                bf16x8 bhi = *(const bf16x8*)&Bs[(c*16 + lr)*128 + kidx];
                bf16x8 blo = *(const bf16x8*)&Bs[16384 + (c*16 + lr)*128 + kidx];
                acc[c] = __builtin_amdgcn_mfma_f32_16x16x32_bf16(ahi, bhi, acc[c], 0, 0, 0);
                acc[c] = __builtin_amdgcn_mfma_f32_16x16x32_bf16(ahi, blo, acc[c], 0, 0, 0);
            }
        }
    }

    // fused pooling epilogue
    int rbase = r0 + ((lane >> 4) << 2);
    int g[4];
    #pragma unroll
    for(int i = 0; i < 4; ++i){
        int crow = rbase + i;
        g[i] = (crow < n) ? batch[crow] : -1;
    }
    int gf = __shfl(g[0], 0);
    bool uni = __all(g[0]==gf && g[1]==gf && g[2]==gf && g[3]==gf && gf >= 0);

    #pragma unroll
    for(int c = 0; c < 8; ++c){
        int ccol = c*16 + lr;
        float bcol = bias[ccol];
        if(uni){
            float s = (acc[c][0]+bcol) + (acc[c][1]+bcol) + (acc[c][2]+bcol) + (acc[c][3]+bcol);
            s += __shfl_xor(s, 16);
            s += __shfl_xor(s, 32);
            if(lane < 16) atomicAdd(&pooled[gf*128 + ccol], s);
        } else {
            #pragma unroll
            for(int i = 0; i < 4; ++i){
                if(g[i] >= 0) atomicAdd(&pooled[g[i]*128 + ccol], acc[c][i] + bcol);
            }
        }
    }
}

// ---------------- pull aggregation (bf16 in/out, f32 accumulate) ----------------

__global__ __launch_bounds__(256) void aggregate(const unsigned int* __restrict__ y, const int* __restrict__ row_start,
                                                 const int* __restrict__ csr_src, const float* __restrict__ dinv,
                                                 const float* __restrict__ bias, unsigned int* __restrict__ hout, int n){
    int wave = threadIdx.x >> 6;
    int lane = threadIdx.x & 63;
    int node = blockIdx.x*4 + wave;
    if(node >= n) return;
    int s0 = row_start[node];
    int s1 = row_start[node+1];

    unsigned int self = y[(size_t)node*64 + lane];
    float ax[8], ay[8];
    ax[0] = b2f_lo(self); ay[0] = b2f_hi(self);
    #pragma unroll
    for(int u = 1; u < 8; ++u){ ax[u] = 0.f; ay[u] = 0.f; }

    int j = s0;
    for(; j + 8 <= s1; j += 8){
        int idx[8];
        #pragma unroll
        for(int u = 0; u < 8; ++u) idx[u] = csr_src[j+u];
        #pragma unroll
        for(int u = 0; u < 8; ++u){
            unsigned int v = y[(size_t)idx[u]*64 + lane];
            ax[u] += b2f_lo(v); ay[u] += b2f_hi(v);
        }
    }
    int rem = s1 - j;
    int idx[7];
    #pragma unroll
    for(int u = 0; u < 7; ++u) idx[u] = (u < rem) ? csr_src[j+u] : node;
    #pragma unroll
    for(int u = 0; u < 7; ++u){
        unsigned int v = y[(size_t)idx[u]*64 + lane];
        if(u < rem){ ax[u] += b2f_lo(v); ay[u] += b2f_hi(v); }
    }

    float s_x = ((ax[0]+ax[1]) + (ax[2]+ax[3])) + ((ax[4]+ax[5]) + (ax[6]+ax[7]));
    float s_y = ((ay[0]+ay[1]) + (ay[2]+ay[3])) + ((ay[4]+ay[5]) + (ay[6]+ay[7]));
    float dn = dinv[node];
    float bx = bias[lane*2], by = bias[lane*2+1];
    float rx = fmaxf(fmaf(s_x, dn, bx), 0.f);
    float ry = fmaxf(fmaf(s_y, dn, by), 0.f);
    unsigned int packed = ((unsigned int)f2b(ry) << 16) | (unsigned int)f2b(rx);
    __builtin_nontemporal_store(packed, &hout[(size_t)node*64 + lane]);
}

// ---------------- MLP head ----------------

__global__ void head_kernel(const float* __restrict__ pooled,
                            const float* __restrict__ Wm1, const float* __restrict__ bm1,
                            const float* __restrict__ Wm2, const float* __restrict__ bm2,
                            float* __restrict__ out){
    __shared__ float p[128];
    __shared__ float tq[128];
    int g = blockIdx.x, j = threadIdx.x;
    p[j] = pooled[g*128 + j];
    __syncthreads();
    float a = bm1[j];
    for(int k = 0; k < 128; ++k) a = fmaf(p[k], Wm1[k*128 + j], a);
    tq[j] = fmaxf(a, 0.f);
    __syncthreads();
    if(j < 10){
        float o = bm2[j];
        for(int k = 0; k < 128; ++k) o = fmaf(tq[k], Wm2[k*10 + j], o);
        out[g*10 + j] = o;
    }
}

// ---------------- launch ----------------

extern "C" void kernel_launch(void* const* d_in, const int* in_sizes, int n_in,
                              void* d_out, int out_size, void* d_ws, size_t ws_size,
                              hipStream_t stream){
    const float* x    = (const float*)d_in[0];
    const int*   ei   = (const int*)  d_in[1];
    const int*   batch= (const int*)  d_in[2];
    const float* W0   = (const float*)d_in[3];
    const float* b0   = (const float*)d_in[4];
    const float* W1   = (const float*)d_in[5];
    const float* b1   = (const float*)d_in[6];
    const float* W2   = (const float*)d_in[7];
    const float* b2   = (const float*)d_in[8];
    const float* Wjk  = (const float*)d_in[9];
    const float* bjk  = (const float*)d_in[10];
    const float* Wm1  = (const float*)d_in[11];
    const float* bm1  = (const float*)d_in[12];
    const float* Wm2  = (const float*)d_in[13];
    const float* bm2  = (const float*)d_in[14];

    const int N = in_sizes[0] / 128;
    const int E = in_sizes[1] / 2;
    const int* src = ei;
    const int* dst = ei + E;

    const int nbuck = (N + (1<<BSHIFT) - 1) >> BSHIFT;            // 49 for N=100k
    const int cap   = E/nbuck + E/(nbuck*4) + 2048;               // mean + 25% + slack

    char* ws = (char*)d_ws;
    size_t off = 0;
    auto take = [&](size_t bytes)->char*{
        char* p = ws + off; off = (off + bytes + 255) & ~(size_t)255; return p;
    };
    unsigned short* Y    = (unsigned short*)take((size_t)N*128*2);    // bf16 row-major
    unsigned short* Habc = (unsigned short*)take((size_t)3*N*128*2);  // bf16 [3][N][128]
    float* dinv    = (float*)take((size_t)N*4);
    int*   deg     = (int*)  take((size_t)N*4);
    int*   cursor  = (int*)  take((size_t)N*4);
    int*   row_start=(int*)  take((size_t)(N+1)*4);
    int*   csr_src = (int*)  take((size_t)E*4 + 64);
    float* pooled  = (float*)take((size_t)512*128*4);
    int*   partials= (int*)  take((size_t)512*4);
    unsigned short* Whi = (unsigned short*)take((size_t)6*16384*2);
    unsigned short* Wlo = (unsigned short*)take((size_t)6*16384*2);
    int*   bcursor = (int*)  take((size_t)64*4);
    int*   stage   = (int*)  take((size_t)nbuck*cap*4);

    (void)hipMemsetAsync(deg,     0, (size_t)N*4, stream);
    (void)hipMemsetAsync(pooled,  0, (size_t)512*128*4, stream);
    (void)hipMemsetAsync(bcursor, 0, (size_t)64*4, stream);

    int nb = (N + 255)/256;
    int bgrid = 8 * ((nbuck + 7)/8) * CPB;

    partition_edges<<<(E + 256*EPT - 1)/(256*EPT), 256, 0, stream>>>(src, dst, E, bcursor, stage, cap);
    hist_b         <<<bgrid, 256, 0, stream>>>(stage, bcursor, cap, nbuck, deg);
    scan_part      <<<nb, 256, 0, stream>>>(deg, N, partials);
    scan_partials_k<<<1, 512, 0, stream>>>(partials, nb);
    scan_final     <<<nb, 256, 0, stream>>>(deg, N, partials, row_start, dinv);
    (void)hipMemcpyAsync(cursor, row_start, (size_t)N*4, hipMemcpyDeviceToDevice, stream);
    fill_b         <<<bgrid, 256, 0, stream>>>(stage, bcursor, cap, nbuck, cursor, csr_src);
    prep_w_all     <<<384, 256, 0, stream>>>(W0, W1, W2, Wjk, Whi, Wlo);

    int gb = (N + 127)/128;
    int ab = (N + 3)/4;
    unsigned short* H0 = Habc;
    unsigned short* H1 = Habc + (size_t)N*128;
    unsigned short* H2 = Habc + (size_t)2*N*128;

    // layer 1 (f32 A)
    gemm_f32A<<<gb, 512, 0, stream>>>(x,  Whi,           Wlo,           dinv, Y, N);
    aggregate<<<ab, 256, 0, stream>>>((const unsigned int*)Y, row_start, csr_src, dinv, b0, (unsigned int*)H0, N);
    // layer 2 (bf16 A)
    gemm_b16A<<<gb, 512, 0, stream>>>(H0, Whi + 1*16384, Wlo + 1*16384, dinv, Y, N);
    aggregate<<<ab, 256, 0, stream>>>((const unsigned int*)Y, row_start, csr_src, dinv, b1, (unsigned int*)H1, N);
    // layer 3 (bf16 A)
    gemm_b16A<<<gb, 512, 0, stream>>>(H1, Whi + 2*16384, Wlo + 2*16384, dinv, Y, N);
    aggregate<<<ab, 256, 0, stream>>>((const unsigned int*)Y, row_start, csr_src, dinv, b2, (unsigned int*)H2, N);
    // JK projection + fused pooling (K=384, bf16 A, 3 staged B-phases)
    gemm_jk_pool<<<gb, 512, 0, stream>>>(Habc, Whi, Wlo, bjk, batch, pooled, N);

    head_kernel<<<512, 128, 0, stream>>>(pooled, Wm1, bm1, Wm2, bm2, (float*)d_out);
}

// Round 10
// 476.754 us; speedup vs baseline: 3.3983x; 1.0255x over previous
//
#include <hip/hip_runtime.h>

typedef __attribute__((ext_vector_type(8))) short bf16x8;
typedef __attribute__((ext_vector_type(4))) float f32x4;

#define BSHIFT 11
#define EPT 8
#define CPB 16   // chunks (blocks) per bucket in hist_b/fill_b

__device__ inline unsigned short f2b(float x){
    union{float f; unsigned int u;} c; c.f = x;
    unsigned int r = c.u + 0x7fffu + ((c.u >> 16) & 1u);
    return (unsigned short)(r >> 16);
}
__device__ inline float b2f_lo(unsigned int u){
    union{unsigned int u; float f;} c; c.u = u << 16; return c.f;
}
__device__ inline float b2f_hi(unsigned int u){
    union{unsigned int u; float f;} c; c.u = u & 0xffff0000u; return c.f;
}

// ---------------- bucketed CSR build ----------------

__global__ __launch_bounds__(256) void partition_edges(const int* __restrict__ src, const int* __restrict__ dst,
                                                       int E, int* __restrict__ bcursor,
                                                       int* __restrict__ stage, int cap){
    __shared__ int lcount[64];
    __shared__ int lbase[64];
    int t = threadIdx.x;
    if(t < 64) lcount[t] = 0;
    __syncthreads();
    int e0 = blockIdx.x*256*EPT + t;
    int b[EPT], rank[EPT], v[EPT];
    #pragma unroll
    for(int i = 0; i < EPT; ++i){
        int e = e0 + i*256;
        bool ok = e < E;
        int d = ok ? dst[e] : 0;
        int s = ok ? src[e] : 0;
        b[i] = d >> BSHIFT;
        v[i] = (s << BSHIFT) | (d & ((1<<BSHIFT)-1));
        rank[i] = ok ? atomicAdd(&lcount[b[i]], 1) : -1;
    }
    __syncthreads();
    if(t < 64){
        int c = lcount[t];
        lbase[t] = (c > 0) ? atomicAdd(&bcursor[t], c) : 0;
    }
    __syncthreads();
    #pragma unroll
    for(int i = 0; i < EPT; ++i){
        if(rank[i] >= 0){
            int pos = lbase[b[i]] + rank[i];
            if(pos < cap) stage[(size_t)b[i]*cap + pos] = v[i];
        }
    }
}

__global__ __launch_bounds__(256) void hist_b(const int* __restrict__ stage, const int* __restrict__ bcnt,
                                              int cap, int nb, int* __restrict__ deg){
    int xcd = blockIdx.x & 7, slot = blockIdx.x >> 3;
    int bwx = slot / CPB, chunk = slot - bwx*CPB;
    int b = bwx*8 + xcd;
    if(b >= nb) return;
    int cnt = bcnt[b]; if(cnt > cap) cnt = cap;
    int dbase = b << BSHIFT;
    const int* sp = stage + (size_t)b*cap;
    for(int i = chunk*256 + threadIdx.x; i < cnt; i += CPB*256){
        int v = sp[i];
        atomicAdd(&deg[dbase + (v & ((1<<BSHIFT)-1))], 1);
    }
}

__global__ __launch_bounds__(256) void fill_b(const int* __restrict__ stage, const int* __restrict__ bcnt,
                                              int cap, int nb, int* __restrict__ cursor,
                                              int* __restrict__ csr_src){
    int xcd = blockIdx.x & 7, slot = blockIdx.x >> 3;
    int bwx = slot / CPB, chunk = slot - bwx*CPB;
    int b = bwx*8 + xcd;
    if(b >= nb) return;
    int cnt = bcnt[b]; if(cnt > cap) cnt = cap;
    int dbase = b << BSHIFT;
    const int* sp = stage + (size_t)b*cap;
    for(int i = chunk*256 + threadIdx.x; i < cnt; i += CPB*256){
        int v = sp[i];
        int p = atomicAdd(&cursor[dbase + (v & ((1<<BSHIFT)-1))], 1);
        csr_src[p] = v >> BSHIFT;
    }
}

// ---------------- scans ----------------

__global__ void scan_part(const int* __restrict__ deg, int n, int* __restrict__ partials){
    __shared__ int sm[256];
    int t = threadIdx.x;
    int idx = blockIdx.x*256 + t;
    sm[t] = (idx < n) ? deg[idx] : 0;
    __syncthreads();
    for(int s = 128; s > 0; s >>= 1){ if(t < s) sm[t] += sm[t+s]; __syncthreads(); }
    if(t == 0) partials[blockIdx.x] = sm[0];
}

__global__ void scan_partials_k(int* __restrict__ partials, int nb){
    __shared__ int sm[512];
    int t = threadIdx.x;
    int orig = (t < nb) ? partials[t] : 0;
    sm[t] = orig; __syncthreads();
    for(int s = 1; s < 512; s <<= 1){
        int add = (t >= s) ? sm[t-s] : 0;
        __syncthreads();
        sm[t] += add;
        __syncthreads();
    }
    if(t < nb) partials[t] = sm[t] - orig;   // exclusive
}

__global__ void scan_final(const int* __restrict__ deg, int n,
                           const int* __restrict__ partials, int* __restrict__ row_start,
                           int* __restrict__ cursor, float* __restrict__ dinv){
    __shared__ int sm[256];
    int t = threadIdx.x;
    int idx = blockIdx.x*256 + t;
    int orig = (idx < n) ? deg[idx] : 0;
    sm[t] = orig; __syncthreads();
    for(int s = 1; s < 256; s <<= 1){
        int add = (t >= s) ? sm[t-s] : 0;
        __syncthreads();
        sm[t] += add;
        __syncthreads();
    }
    int excl = partials[blockIdx.x] + sm[t] - orig;
    if(idx < n){
        row_start[idx] = excl;
        cursor[idx]    = excl;      // fill_b start positions (was a d2d memcpy)
        dinv[idx] = rsqrtf((float)orig + 1.0f);
    }
    if(idx == n-1) row_start[n] = excl + orig;   // == E
}

// ---------------- weight prep: f32 -> transposed, XOR-swizzled bf16 hi/lo ----------------
// Square layers (m<3) use hi only; JK blocks (m>=3) keep hi+lo split.

__device__ inline void split_bf16(float x, unsigned short& h, unsigned short& l){
    union { float f; unsigned int u; } cv;
    cv.f = x;
    unsigned int u = cv.u;
    unsigned int rh = u + 0x7fffu + ((u >> 16) & 1u);
    h = (unsigned short)(rh >> 16);
    union { unsigned int u; float f; } hb;
    hb.u = ((unsigned int)h) << 16;
    float r = x - hb.f;
    cv.f = r;
    unsigned int u2 = cv.u;
    unsigned int rl = u2 + 0x7fffu + ((u2 >> 16) & 1u);
    l = (unsigned short)(rl >> 16);
}

__global__ void prep_w_all(const float* __restrict__ W0, const float* __restrict__ W1,
                           const float* __restrict__ W2, const float* __restrict__ Wjk,
                           unsigned short* __restrict__ hi, unsigned short* __restrict__ lo){
    int m = blockIdx.x >> 6;                         // 0..5
    int i = (blockIdx.x & 63)*256 + threadIdx.x;     // 0..16383
    const float* W = (m==0) ? W0 : (m==1) ? W1 : (m==2) ? W2 : (Wjk + (m-3)*16384);
    int k = i >> 7, c = i & 127;                     // W is [k][c]
    unsigned short h, l;
    split_bf16(W[i], h, l);
    size_t o = (size_t)m*16384 + c*128 + (k ^ ((c & 7) << 3));
    hi[o] = h;
    if(m >= 3) lo[o] = l;
}

// ---------------- GEMM (layer 1): out_bf16 = (x_f32 @ W_hi) * dinv_row ----------------
// 512 threads, 32KB LDS (hi only) -> 4 blocks/CU. Split-A 2-MFMA (exact A, bf16 W).

__global__ __launch_bounds__(512) void gemm_f32A(const float* __restrict__ in,
                                                 const unsigned short* __restrict__ Wt_hi,
                                                 const float* __restrict__ dinv,
                                                 unsigned short* __restrict__ out, int n){
    __shared__ __align__(16) unsigned short Bs[16384];
    int t = threadIdx.x;
    int lane = t & 63;
    int r0 = blockIdx.x*128 + (t >> 6)*16;
    int lr = lane & 15;
    int lk = (lane >> 4) * 8;

    {
        uint4* d = (uint4*)Bs;
        const uint4* sH = (const uint4*)Wt_hi;
        #pragma unroll
        for(int i = 0; i < 4; ++i) d[t + i*512] = sH[t + i*512];
    }
    __syncthreads();

    f32x4 acc[8];
    #pragma unroll
    for(int c = 0; c < 8; ++c) acc[c] = (f32x4){0.f, 0.f, 0.f, 0.f};

    int arow_i = r0 + lr; if(arow_i > n-1) arow_i = n-1;
    const float* arow = in + (size_t)arow_i*128;

    #pragma unroll
    for(int k0 = 0; k0 < 128; k0 += 32){
        f32x4 a0 = *(const f32x4*)(arow + k0 + lk);
        f32x4 a1 = *(const f32x4*)(arow + k0 + lk + 4);
        bf16x8 ahi, alo;
        #pragma unroll
        for(int j = 0; j < 4; ++j){
            unsigned short h, l;
            split_bf16(a0[j], h, l);
            ahi[j] = (short)h; alo[j] = (short)l;
            split_bf16(a1[j], h, l);
            ahi[j+4] = (short)h; alo[j+4] = (short)l;
        }
        int kidx = (k0 + lk) ^ ((lr & 7) << 3);
        #pragma unroll
        for(int c = 0; c < 8; ++c){
            bf16x8 bhi = *(const bf16x8*)&Bs[(c*16 + lr)*128 + kidx];
            acc[c] = __builtin_amdgcn_mfma_f32_16x16x32_bf16(ahi, bhi, acc[c], 0, 0, 0);
            acc[c] = __builtin_amdgcn_mfma_f32_16x16x32_bf16(alo, bhi, acc[c], 0, 0, 0);
        }
    }

    float dv[4];
    #pragma unroll
    for(int i = 0; i < 4; ++i){
        int cr = r0 + ((lane >> 4) << 2) + i; if(cr > n-1) cr = n-1;
        dv[i] = dinv[cr];
    }
    #pragma unroll
    for(int c = 0; c < 8; ++c){
        int ccol = c*16 + lr;
        #pragma unroll
        for(int i = 0; i < 4; ++i){
            int crow = r0 + ((lane >> 4) << 2) + i;
            if(crow < n) out[(size_t)crow*128 + ccol] = f2b(acc[c][i] * dv[i]);
        }
    }
}

// ---------------- GEMM (layers 2,3): bf16 A, bf16 W (hi only), 1 MFMA/frag ----------------

__global__ __launch_bounds__(512) void gemm_b16A(const unsigned short* __restrict__ in,
                                                 const unsigned short* __restrict__ Wt_hi,
                                                 const float* __restrict__ dinv,
                                                 unsigned short* __restrict__ out, int n){
    __shared__ __align__(16) unsigned short Bs[16384];
    int t = threadIdx.x;
    int lane = t & 63;
    int r0 = blockIdx.x*128 + (t >> 6)*16;
    int lr = lane & 15;
    int lk = (lane >> 4) * 8;

    {
        uint4* d = (uint4*)Bs;
        const uint4* sH = (const uint4*)Wt_hi;
        #pragma unroll
        for(int i = 0; i < 4; ++i) d[t + i*512] = sH[t + i*512];
    }
    __syncthreads();

    f32x4 acc[8];
    #pragma unroll
    for(int c = 0; c < 8; ++c) acc[c] = (f32x4){0.f, 0.f, 0.f, 0.f};

    int arow_i = r0 + lr; if(arow_i > n-1) arow_i = n-1;
    const unsigned short* arow = in + (size_t)arow_i*128;

    #pragma unroll
    for(int k0 = 0; k0 < 128; k0 += 32){
        bf16x8 ahi = *(const bf16x8*)(arow + k0 + lk);
        int kidx = (k0 + lk) ^ ((lr & 7) << 3);
        #pragma unroll
        for(int c = 0; c < 8; ++c){
            bf16x8 bhi = *(const bf16x8*)&Bs[(c*16 + lr)*128 + kidx];
            acc[c] = __builtin_amdgcn_mfma_f32_16x16x32_bf16(ahi, bhi, acc[c], 0, 0, 0);
        }
    }

    float dv[4];
    #pragma unroll
    for(int i = 0; i < 4; ++i){
        int cr = r0 + ((lane >> 4) << 2) + i; if(cr > n-1) cr = n-1;
        dv[i] = dinv[cr];
    }
    #pragma unroll
    for(int c = 0; c < 8; ++c){
        int ccol = c*16 + lr;
        #pragma unroll
        for(int i = 0; i < 4; ++i){
            int crow = r0 + ((lane >> 4) << 2) + i;
            if(crow < n) out[(size_t)crow*128 + ccol] = f2b(acc[c][i] * dv[i]);
        }
    }
}

// ---------------- JK GEMM + fused pooling (keeps hi/lo W split) ----------------

__global__ __launch_bounds__(512) void gemm_jk_pool(const unsigned short* __restrict__ habc,
                                                    const unsigned short* __restrict__ Whi,
                                                    const unsigned short* __restrict__ Wlo,
                                                    const float* __restrict__ bias,
                                                    const int* __restrict__ batch,
                                                    float* __restrict__ pooled, int n){
    __shared__ __align__(16) unsigned short Bs[32768];
    int t = threadIdx.x;
    int lane = t & 63;
    int r0 = blockIdx.x*128 + (t >> 6)*16;
    int lr = lane & 15;
    int lk = (lane >> 4) * 8;

    f32x4 acc[8];
    #pragma unroll
    for(int c = 0; c < 8; ++c) acc[c] = (f32x4){0.f, 0.f, 0.f, 0.f};

    int arow_i = r0 + lr; if(arow_i > n-1) arow_i = n-1;

    for(int kb3 = 0; kb3 < 3; ++kb3){
        __syncthreads();
        {
            uint4* d = (uint4*)Bs;
            const uint4* sH = (const uint4*)(Whi + (size_t)(3 + kb3)*16384);
            const uint4* sL = (const uint4*)(Wlo + (size_t)(3 + kb3)*16384);
            #pragma unroll
            for(int i = 0; i < 4; ++i){
                d[t + i*512]        = sH[t + i*512];
                d[2048 + t + i*512] = sL[t + i*512];
            }
        }
        __syncthreads();

        const unsigned short* arow = habc + (size_t)kb3*n*128 + (size_t)arow_i*128;
        #pragma unroll
        for(int k0 = 0; k0 < 128; k0 += 32){
            bf16x8 ahi = *(const bf16x8*)(arow + k0 + lk);
            int kidx = (k0 + lk) ^ ((lr & 7) << 3);
            #pragma unroll
            for(int c = 0; c < 8; ++c){
                bf16x8 bhi = *(const bf16x8*)&Bs[(c*16 + lr)*128 + kidx];
                bf16x8 blo = *(const bf16x8*)&Bs[16384 + (c*16 + lr)*128 + kidx];
                acc[c] = __builtin_amdgcn_mfma_f32_16x16x32_bf16(ahi, bhi, acc[c], 0, 0, 0);
                acc[c] = __builtin_amdgcn_mfma_f32_16x16x32_bf16(ahi, blo, acc[c], 0, 0, 0);
            }
        }
    }

    // fused pooling epilogue
    int rbase = r0 + ((lane >> 4) << 2);
    int g[4];
    #pragma unroll
    for(int i = 0; i < 4; ++i){
        int crow = rbase + i;
        g[i] = (crow < n) ? batch[crow] : -1;
    }
    int gf = __shfl(g[0], 0);
    bool uni = __all(g[0]==gf && g[1]==gf && g[2]==gf && g[3]==gf && gf >= 0);

    #pragma unroll
    for(int c = 0; c < 8; ++c){
        int ccol = c*16 + lr;
        float bcol = bias[ccol];
        if(uni){
            float s = (acc[c][0]+bcol) + (acc[c][1]+bcol) + (acc[c][2]+bcol) + (acc[c][3]+bcol);
            s += __shfl_xor(s, 16);
            s += __shfl_xor(s, 32);
            if(lane < 16) atomicAdd(&pooled[gf*128 + ccol], s);
        } else {
            #pragma unroll
            for(int i = 0; i < 4; ++i){
                if(g[i] >= 0) atomicAdd(&pooled[g[i]*128 + ccol], acc[c][i] + bcol);
            }
        }
    }
}

// ---------------- pull aggregation (bf16 in/out, f32 accumulate) ----------------

__global__ __launch_bounds__(256) void aggregate(const unsigned int* __restrict__ y, const int* __restrict__ row_start,
                                                 const int* __restrict__ csr_src, const float* __restrict__ dinv,
                                                 const float* __restrict__ bias, unsigned int* __restrict__ hout, int n){
    int wave = threadIdx.x >> 6;
    int lane = threadIdx.x & 63;
    int node = blockIdx.x*4 + wave;
    if(node >= n) return;
    int s0 = row_start[node];
    int s1 = row_start[node+1];

    unsigned int self = y[(size_t)node*64 + lane];
    float ax[8], ay[8];
    ax[0] = b2f_lo(self); ay[0] = b2f_hi(self);
    #pragma unroll
    for(int u = 1; u < 8; ++u){ ax[u] = 0.f; ay[u] = 0.f; }

    int j = s0;
    for(; j + 8 <= s1; j += 8){
        int idx[8];
        #pragma unroll
        for(int u = 0; u < 8; ++u) idx[u] = csr_src[j+u];
        #pragma unroll
        for(int u = 0; u < 8; ++u){
            unsigned int v = y[(size_t)idx[u]*64 + lane];
            ax[u] += b2f_lo(v); ay[u] += b2f_hi(v);
        }
    }
    int rem = s1 - j;
    int idx[7];
    #pragma unroll
    for(int u = 0; u < 7; ++u) idx[u] = (u < rem) ? csr_src[j+u] : node;
    #pragma unroll
    for(int u = 0; u < 7; ++u){
        unsigned int v = y[(size_t)idx[u]*64 + lane];
        if(u < rem){ ax[u] += b2f_lo(v); ay[u] += b2f_hi(v); }
    }

    float s_x = ((ax[0]+ax[1]) + (ax[2]+ax[3])) + ((ax[4]+ax[5]) + (ax[6]+ax[7]));
    float s_y = ((ay[0]+ay[1]) + (ay[2]+ay[3])) + ((ay[4]+ay[5]) + (ay[6]+ay[7]));
    float dn = dinv[node];
    float bx = bias[lane*2], by = bias[lane*2+1];
    float rx = fmaxf(fmaf(s_x, dn, bx), 0.f);
    float ry = fmaxf(fmaf(s_y, dn, by), 0.f);
    unsigned int packed = ((unsigned int)f2b(ry) << 16) | (unsigned int)f2b(rx);
    __builtin_nontemporal_store(packed, &hout[(size_t)node*64 + lane]);
}

// ---------------- MLP head ----------------

__global__ void head_kernel(const float* __restrict__ pooled,
                            const float* __restrict__ Wm1, const float* __restrict__ bm1,
                            const float* __restrict__ Wm2, const float* __restrict__ bm2,
                            float* __restrict__ out){
    __shared__ float p[128];
    __shared__ float tq[128];
    int g = blockIdx.x, j = threadIdx.x;
    p[j] = pooled[g*128 + j];
    __syncthreads();
    float a = bm1[j];
    for(int k = 0; k < 128; ++k) a = fmaf(p[k], Wm1[k*128 + j], a);
    tq[j] = fmaxf(a, 0.f);
    __syncthreads();
    if(j < 10){
        float o = bm2[j];
        for(int k = 0; k < 128; ++k) o = fmaf(tq[k], Wm2[k*10 + j], o);
        out[g*10 + j] = o;
    }
}

// ---------------- launch ----------------

extern "C" void kernel_launch(void* const* d_in, const int* in_sizes, int n_in,
                              void* d_out, int out_size, void* d_ws, size_t ws_size,
                              hipStream_t stream){
    const float* x    = (const float*)d_in[0];
    const int*   ei   = (const int*)  d_in[1];
    const int*   batch= (const int*)  d_in[2];
    const float* W0   = (const float*)d_in[3];
    const float* b0   = (const float*)d_in[4];
    const float* W1   = (const float*)d_in[5];
    const float* b1   = (const float*)d_in[6];
    const float* W2   = (const float*)d_in[7];
    const float* b2   = (const float*)d_in[8];
    const float* Wjk  = (const float*)d_in[9];
    const float* bjk  = (const float*)d_in[10];
    const float* Wm1  = (const float*)d_in[11];
    const float* bm1  = (const float*)d_in[12];
    const float* Wm2  = (const float*)d_in[13];
    const float* bm2  = (const float*)d_in[14];

    const int N = in_sizes[0] / 128;
    const int E = in_sizes[1] / 2;
    const int* src = ei;
    const int* dst = ei + E;

    const int nbuck = (N + (1<<BSHIFT) - 1) >> BSHIFT;            // 49 for N=100k
    const int cap   = E/nbuck + E/(nbuck*4) + 2048;               // mean + 25% + slack

    char* ws = (char*)d_ws;
    size_t off = 0;
    auto take = [&](size_t bytes)->char*{
        char* p = ws + off; off = (off + bytes + 255) & ~(size_t)255; return p;
    };
    unsigned short* Y    = (unsigned short*)take((size_t)N*128*2);    // bf16 row-major
    unsigned short* Habc = (unsigned short*)take((size_t)3*N*128*2);  // bf16 [3][N][128]
    float* dinv    = (float*)take((size_t)N*4);
    int*   deg     = (int*)  take((size_t)N*4);
    int*   cursor  = (int*)  take((size_t)N*4);
    int*   row_start=(int*)  take((size_t)(N+1)*4);
    int*   csr_src = (int*)  take((size_t)E*4 + 64);
    float* pooled  = (float*)take((size_t)512*128*4);
    int*   partials= (int*)  take((size_t)512*4);
    unsigned short* Whi = (unsigned short*)take((size_t)6*16384*2);
    unsigned short* Wlo = (unsigned short*)take((size_t)6*16384*2);
    int*   bcursor = (int*)  take((size_t)64*4);
    int*   stage   = (int*)  take((size_t)nbuck*cap*4);

    (void)hipMemsetAsync(deg,     0, (size_t)N*4, stream);
    (void)hipMemsetAsync(pooled,  0, (size_t)512*128*4, stream);
    (void)hipMemsetAsync(bcursor, 0, (size_t)64*4, stream);

    int nb = (N + 255)/256;
    int bgrid = 8 * ((nbuck + 7)/8) * CPB;

    partition_edges<<<(E + 256*EPT - 1)/(256*EPT), 256, 0, stream>>>(src, dst, E, bcursor, stage, cap);
    hist_b         <<<bgrid, 256, 0, stream>>>(stage, bcursor, cap, nbuck, deg);
    scan_part      <<<nb, 256, 0, stream>>>(deg, N, partials);
    scan_partials_k<<<1, 512, 0, stream>>>(partials, nb);
    scan_final     <<<nb, 256, 0, stream>>>(deg, N, partials, row_start, cursor, dinv);
    fill_b         <<<bgrid, 256, 0, stream>>>(stage, bcursor, cap, nbuck, cursor, csr_src);
    prep_w_all     <<<384, 256, 0, stream>>>(W0, W1, W2, Wjk, Whi, Wlo);

    int gb = (N + 127)/128;
    int ab = (N + 3)/4;
    unsigned short* H0 = Habc;
    unsigned short* H1 = Habc + (size_t)N*128;
    unsigned short* H2 = Habc + (size_t)2*N*128;

    // layer 1 (f32 A, bf16 W)
    gemm_f32A<<<gb, 512, 0, stream>>>(x,  Whi,           dinv, Y, N);
    aggregate<<<ab, 256, 0, stream>>>((const unsigned int*)Y, row_start, csr_src, dinv, b0, (unsigned int*)H0, N);
    // layer 2 (bf16 A, bf16 W)
    gemm_b16A<<<gb, 512, 0, stream>>>(H0, Whi + 1*16384, dinv, Y, N);
    aggregate<<<ab, 256, 0, stream>>>((const unsigned int*)Y, row_start, csr_src, dinv, b1, (unsigned int*)H1, N);
    // layer 3 (bf16 A, bf16 W)
    gemm_b16A<<<gb, 512, 0, stream>>>(H1, Whi + 2*16384, dinv, Y, N);
    aggregate<<<ab, 256, 0, stream>>>((const unsigned int*)Y, row_start, csr_src, dinv, b2, (unsigned int*)H2, N);
    // JK projection + fused pooling (K=384, hi/lo split W)
    gemm_jk_pool<<<gb, 512, 0, stream>>>(Habc, Whi, Wlo, bjk, batch, pooled, N);

    head_kernel<<<512, 128, 0, stream>>>(pooled, Wm1, bm1, Wm2, bm2, (float*)d_out);
}

// Round 11
// 448.212 us; speedup vs baseline: 3.6147x; 1.0637x over previous
//
#include <hip/hip_runtime.h>

typedef __attribute__((ext_vector_type(8))) short bf16x8;
typedef __attribute__((ext_vector_type(4))) float f32x4;

#define BSHIFT 11
#define EPT 8
#define CPB 16   // chunks (blocks) per bucket in hist_b/fill_b

__device__ inline unsigned short f2b(float x){
    union{float f; unsigned int u;} c; c.f = x;
    unsigned int r = c.u + 0x7fffu + ((c.u >> 16) & 1u);
    return (unsigned short)(r >> 16);
}
__device__ inline float b2f_lo(unsigned int u){
    union{unsigned int u; float f;} c; c.u = u << 16; return c.f;
}
__device__ inline float b2f_hi(unsigned int u){
    union{unsigned int u; float f;} c; c.u = u & 0xffff0000u; return c.f;
}

// ---------------- bucketed CSR build ----------------
// partition: zero deg (grid-stride), then scatter packed (src<<11 | dst&2047) to dst buckets.

__global__ __launch_bounds__(256) void partition_edges(const int* __restrict__ src, const int* __restrict__ dst,
                                                       int E, int n, int* __restrict__ deg,
                                                       int* __restrict__ bcursor,
                                                       int* __restrict__ stage, int cap){
    __shared__ int lcount[64];
    __shared__ int lbase[64];
    int t = threadIdx.x;
    for(int i = blockIdx.x*256 + t; i < n; i += gridDim.x*256) deg[i] = 0;   // consumer hist_b is a later dispatch
    if(t < 64) lcount[t] = 0;
    __syncthreads();
    int e0 = blockIdx.x*256*EPT + t;
    int b[EPT], rank[EPT], v[EPT];
    #pragma unroll
    for(int i = 0; i < EPT; ++i){
        int e = e0 + i*256;
        bool ok = e < E;
        int d = ok ? dst[e] : 0;
        int s = ok ? src[e] : 0;
        b[i] = d >> BSHIFT;
        v[i] = (s << BSHIFT) | (d & ((1<<BSHIFT)-1));
        rank[i] = ok ? atomicAdd(&lcount[b[i]], 1) : -1;
    }
    __syncthreads();
    if(t < 64){
        int c = lcount[t];
        lbase[t] = (c > 0) ? atomicAdd(&bcursor[t], c) : 0;
    }
    __syncthreads();
    #pragma unroll
    for(int i = 0; i < EPT; ++i){
        if(rank[i] >= 0){
            int pos = lbase[b[i]] + rank[i];
            if(pos < cap) stage[(size_t)b[i]*cap + pos] = v[i];
        }
    }
}

__global__ __launch_bounds__(256) void hist_b(const int* __restrict__ stage, const int* __restrict__ bcnt,
                                              int cap, int nb, int* __restrict__ deg){
    int xcd = blockIdx.x & 7, slot = blockIdx.x >> 3;
    int bwx = slot / CPB, chunk = slot - bwx*CPB;
    int b = bwx*8 + xcd;
    if(b >= nb) return;
    int cnt = bcnt[b]; if(cnt > cap) cnt = cap;
    int dbase = b << BSHIFT;
    const int* sp = stage + (size_t)b*cap;
    for(int i = chunk*256 + threadIdx.x; i < cnt; i += CPB*256){
        int v = sp[i];
        atomicAdd(&deg[dbase + (v & ((1<<BSHIFT)-1))], 1);
    }
}

__global__ __launch_bounds__(256) void fill_b(const int* __restrict__ stage, const int* __restrict__ bcnt,
                                              int cap, int nb, int* __restrict__ cursor,
                                              int* __restrict__ csr_src){
    int xcd = blockIdx.x & 7, slot = blockIdx.x >> 3;
    int bwx = slot / CPB, chunk = slot - bwx*CPB;
    int b = bwx*8 + xcd;
    if(b >= nb) return;
    int cnt = bcnt[b]; if(cnt > cap) cnt = cap;
    int dbase = b << BSHIFT;
    const int* sp = stage + (size_t)b*cap;
    for(int i = chunk*256 + threadIdx.x; i < cnt; i += CPB*256){
        int v = sp[i];
        int p = atomicAdd(&cursor[dbase + (v & ((1<<BSHIFT)-1))], 1);
        csr_src[p] = v >> BSHIFT;
    }
}

// ---------------- scans ----------------

__global__ void scan_part(const int* __restrict__ deg, int n, int* __restrict__ partials){
    __shared__ int sm[256];
    int t = threadIdx.x;
    int idx = blockIdx.x*256 + t;
    sm[t] = (idx < n) ? deg[idx] : 0;
    __syncthreads();
    for(int s = 128; s > 0; s >>= 1){ if(t < s) sm[t] += sm[t+s]; __syncthreads(); }
    if(t == 0) partials[blockIdx.x] = sm[0];
}

__global__ void scan_partials_k(int* __restrict__ partials, int nb){
    __shared__ int sm[512];
    int t = threadIdx.x;
    int orig = (t < nb) ? partials[t] : 0;
    sm[t] = orig; __syncthreads();
    for(int s = 1; s < 512; s <<= 1){
        int add = (t >= s) ? sm[t-s] : 0;
        __syncthreads();
        sm[t] += add;
        __syncthreads();
    }
    if(t < nb) partials[t] = sm[t] - orig;   // exclusive
}

__global__ void scan_final(const int* __restrict__ deg, int n,
                           const int* __restrict__ partials, int* __restrict__ row_start,
                           int* __restrict__ cursor, float* __restrict__ dinv){
    __shared__ int sm[256];
    int t = threadIdx.x;
    int idx = blockIdx.x*256 + t;
    int orig = (idx < n) ? deg[idx] : 0;
    sm[t] = orig; __syncthreads();
    for(int s = 1; s < 256; s <<= 1){
        int add = (t >= s) ? sm[t-s] : 0;
        __syncthreads();
        sm[t] += add;
        __syncthreads();
    }
    int excl = partials[blockIdx.x] + sm[t] - orig;
    if(idx < n){
        row_start[idx] = excl;
        cursor[idx]    = excl;
        dinv[idx] = rsqrtf((float)orig + 1.0f);
    }
    if(idx == n-1) row_start[n] = excl + orig;   // == E
}

// ---------------- weight prep: f32 -> transposed, XOR-swizzled bf16 (hi only, all 6 tables) ----
// Runs FIRST; spare threads zero pooled and bcursor (both consumed by later dispatches).

__global__ void prep_w_all(const float* __restrict__ W0, const float* __restrict__ W1,
                           const float* __restrict__ W2, const float* __restrict__ Wjk,
                           unsigned short* __restrict__ hi,
                           float* __restrict__ pooled, int* __restrict__ bcursor){
    int m = blockIdx.x >> 6;                         // 0..5
    int i = (blockIdx.x & 63)*256 + threadIdx.x;     // 0..16383
    int tid = blockIdx.x*256 + threadIdx.x;
    if(tid < 512*128) pooled[tid] = 0.f;
    if(tid < 64) bcursor[tid] = 0;
    const float* W = (m==0) ? W0 : (m==1) ? W1 : (m==2) ? W2 : (Wjk + (m-3)*16384);
    int k = i >> 7, c = i & 127;                     // W is [k][c]
    hi[(size_t)m*16384 + c*128 + (k ^ ((c & 7) << 3))] = f2b(W[i]);
}

// ---------------- GEMM (layer 1): out_bf16 = (bf16(x_f32) @ W_hi) * dinv_row ----------------
// 512 threads, 32KB LDS, 1 MFMA/frag (A converted to bf16 in-register).

__global__ __launch_bounds__(512) void gemm_f32A(const float* __restrict__ in,
                                                 const unsigned short* __restrict__ Wt_hi,
                                                 const float* __restrict__ dinv,
                                                 unsigned short* __restrict__ out, int n){
    __shared__ __align__(16) unsigned short Bs[16384];
    int t = threadIdx.x;
    int lane = t & 63;
    int r0 = blockIdx.x*128 + (t >> 6)*16;
    int lr = lane & 15;
    int lk = (lane >> 4) * 8;

    {
        uint4* d = (uint4*)Bs;
        const uint4* sH = (const uint4*)Wt_hi;
        #pragma unroll
        for(int i = 0; i < 4; ++i) d[t + i*512] = sH[t + i*512];
    }
    __syncthreads();

    f32x4 acc[8];
    #pragma unroll
    for(int c = 0; c < 8; ++c) acc[c] = (f32x4){0.f, 0.f, 0.f, 0.f};

    int arow_i = r0 + lr; if(arow_i > n-1) arow_i = n-1;
    const float* arow = in + (size_t)arow_i*128;

    #pragma unroll
    for(int k0 = 0; k0 < 128; k0 += 32){
        f32x4 a0 = *(const f32x4*)(arow + k0 + lk);
        f32x4 a1 = *(const f32x4*)(arow + k0 + lk + 4);
        bf16x8 ahi;
        #pragma unroll
        for(int j = 0; j < 4; ++j){
            ahi[j]   = (short)f2b(a0[j]);
            ahi[j+4] = (short)f2b(a1[j]);
        }
        int kidx = (k0 + lk) ^ ((lr & 7) << 3);
        #pragma unroll
        for(int c = 0; c < 8; ++c){
            bf16x8 bhi = *(const bf16x8*)&Bs[(c*16 + lr)*128 + kidx];
            acc[c] = __builtin_amdgcn_mfma_f32_16x16x32_bf16(ahi, bhi, acc[c], 0, 0, 0);
        }
    }

    float dv[4];
    #pragma unroll
    for(int i = 0; i < 4; ++i){
        int cr = r0 + ((lane >> 4) << 2) + i; if(cr > n-1) cr = n-1;
        dv[i] = dinv[cr];
    }
    #pragma unroll
    for(int c = 0; c < 8; ++c){
        int ccol = c*16 + lr;
        #pragma unroll
        for(int i = 0; i < 4; ++i){
            int crow = r0 + ((lane >> 4) << 2) + i;
            if(crow < n) out[(size_t)crow*128 + ccol] = f2b(acc[c][i] * dv[i]);
        }
    }
}

// ---------------- GEMM (layers 2,3): bf16 A, bf16 W, 1 MFMA/frag ----------------

__global__ __launch_bounds__(512) void gemm_b16A(const unsigned short* __restrict__ in,
                                                 const unsigned short* __restrict__ Wt_hi,
                                                 const float* __restrict__ dinv,
                                                 unsigned short* __restrict__ out, int n){
    __shared__ __align__(16) unsigned short Bs[16384];
    int t = threadIdx.x;
    int lane = t & 63;
    int r0 = blockIdx.x*128 + (t >> 6)*16;
    int lr = lane & 15;
    int lk = (lane >> 4) * 8;

    {
        uint4* d = (uint4*)Bs;
        const uint4* sH = (const uint4*)Wt_hi;
        #pragma unroll
        for(int i = 0; i < 4; ++i) d[t + i*512] = sH[t + i*512];
    }
    __syncthreads();

    f32x4 acc[8];
    #pragma unroll
    for(int c = 0; c < 8; ++c) acc[c] = (f32x4){0.f, 0.f, 0.f, 0.f};

    int arow_i = r0 + lr; if(arow_i > n-1) arow_i = n-1;
    const unsigned short* arow = in + (size_t)arow_i*128;

    #pragma unroll
    for(int k0 = 0; k0 < 128; k0 += 32){
        bf16x8 ahi = *(const bf16x8*)(arow + k0 + lk);
        int kidx = (k0 + lk) ^ ((lr & 7) << 3);
        #pragma unroll
        for(int c = 0; c < 8; ++c){
            bf16x8 bhi = *(const bf16x8*)&Bs[(c*16 + lr)*128 + kidx];
            acc[c] = __builtin_amdgcn_mfma_f32_16x16x32_bf16(ahi, bhi, acc[c], 0, 0, 0);
        }
    }

    float dv[4];
    #pragma unroll
    for(int i = 0; i < 4; ++i){
        int cr = r0 + ((lane >> 4) << 2) + i; if(cr > n-1) cr = n-1;
        dv[i] = dinv[cr];
    }
    #pragma unroll
    for(int c = 0; c < 8; ++c){
        int ccol = c*16 + lr;
        #pragma unroll
        for(int i = 0; i < 4; ++i){
            int crow = r0 + ((lane >> 4) << 2) + i;
            if(crow < n) out[(size_t)crow*128 + ccol] = f2b(acc[c][i] * dv[i]);
        }
    }
}

// ---------------- JK GEMM + fused pooling (bf16 W, 3 × 32KB staged phases) ----------------

__global__ __launch_bounds__(512) void gemm_jk_pool(const unsigned short* __restrict__ habc,
                                                    const unsigned short* __restrict__ Whi,
                                                    const float* __restrict__ bias,
                                                    const int* __restrict__ batch,
                                                    float* __restrict__ pooled, int n){
    __shared__ __align__(16) unsigned short Bs[16384];
    int t = threadIdx.x;
    int lane = t & 63;
    int r0 = blockIdx.x*128 + (t >> 6)*16;
    int lr = lane & 15;
    int lk = (lane >> 4) * 8;

    f32x4 acc[8];
    #pragma unroll
    for(int c = 0; c < 8; ++c) acc[c] = (f32x4){0.f, 0.f, 0.f, 0.f};

    int arow_i = r0 + lr; if(arow_i > n-1) arow_i = n-1;

    for(int kb3 = 0; kb3 < 3; ++kb3){
        __syncthreads();
        {
            uint4* d = (uint4*)Bs;
            const uint4* sH = (const uint4*)(Whi + (size_t)(3 + kb3)*16384);
            #pragma unroll
            for(int i = 0; i < 4; ++i) d[t + i*512] = sH[t + i*512];
        }
        __syncthreads();

        const unsigned short* arow = habc + (size_t)kb3*n*128 + (size_t)arow_i*128;
        #pragma unroll
        for(int k0 = 0; k0 < 128; k0 += 32){
            bf16x8 ahi = *(const bf16x8*)(arow + k0 + lk);
            int kidx = (k0 + lk) ^ ((lr & 7) << 3);
            #pragma unroll
            for(int c = 0; c < 8; ++c){
                bf16x8 bhi = *(const bf16x8*)&Bs[(c*16 + lr)*128 + kidx];
                acc[c] = __builtin_amdgcn_mfma_f32_16x16x32_bf16(ahi, bhi, acc[c], 0, 0, 0);
            }
        }
    }

    // fused pooling epilogue
    int rbase = r0 + ((lane >> 4) << 2);
    int g[4];
    #pragma unroll
    for(int i = 0; i < 4; ++i){
        int crow = rbase + i;
        g[i] = (crow < n) ? batch[crow] : -1;
    }
    int gf = __shfl(g[0], 0);
    bool uni = __all(g[0]==gf && g[1]==gf && g[2]==gf && g[3]==gf && gf >= 0);

    #pragma unroll
    for(int c = 0; c < 8; ++c){
        int ccol = c*16 + lr;
        float bcol = bias[ccol];
        if(uni){
            float s = (acc[c][0]+bcol) + (acc[c][1]+bcol) + (acc[c][2]+bcol) + (acc[c][3]+bcol);
            s += __shfl_xor(s, 16);
            s += __shfl_xor(s, 32);
            if(lane < 16) atomicAdd(&pooled[gf*128 + ccol], s);
        } else {
            #pragma unroll
            for(int i = 0; i < 4; ++i){
                if(g[i] >= 0) atomicAdd(&pooled[g[i]*128 + ccol], acc[c][i] + bcol);
            }
        }
    }
}

// ---------------- pull aggregation (bf16 in/out, f32 accumulate) ----------------

__global__ __launch_bounds__(256) void aggregate(const unsigned int* __restrict__ y, const int* __restrict__ row_start,
                                                 const int* __restrict__ csr_src, const float* __restrict__ dinv,
                                                 const float* __restrict__ bias, unsigned int* __restrict__ hout, int n){
    int wave = threadIdx.x >> 6;
    int lane = threadIdx.x & 63;
    int node = blockIdx.x*4 + wave;
    if(node >= n) return;
    int s0 = row_start[node];
    int s1 = row_start[node+1];

    unsigned int self = y[(size_t)node*64 + lane];
    float ax[8], ay[8];
    ax[0] = b2f_lo(self); ay[0] = b2f_hi(self);
    #pragma unroll
    for(int u = 1; u < 8; ++u){ ax[u] = 0.f; ay[u] = 0.f; }

    int j = s0;
    for(; j + 8 <= s1; j += 8){
        int idx[8];
        #pragma unroll
        for(int u = 0; u < 8; ++u) idx[u] = csr_src[j+u];
        #pragma unroll
        for(int u = 0; u < 8; ++u){
            unsigned int v = y[(size_t)idx[u]*64 + lane];
            ax[u] += b2f_lo(v); ay[u] += b2f_hi(v);
        }
    }
    int rem = s1 - j;
    int idx[7];
    #pragma unroll
    for(int u = 0; u < 7; ++u) idx[u] = (u < rem) ? csr_src[j+u] : node;
    #pragma unroll
    for(int u = 0; u < 7; ++u){
        unsigned int v = y[(size_t)idx[u]*64 + lane];
        if(u < rem){ ax[u] += b2f_lo(v); ay[u] += b2f_hi(v); }
    }

    float s_x = ((ax[0]+ax[1]) + (ax[2]+ax[3])) + ((ax[4]+ax[5]) + (ax[6]+ax[7]));
    float s_y = ((ay[0]+ay[1]) + (ay[2]+ay[3])) + ((ay[4]+ay[5]) + (ay[6]+ay[7]));
    float dn = dinv[node];
    float bx = bias[lane*2], by = bias[lane*2+1];
    float rx = fmaxf(fmaf(s_x, dn, bx), 0.f);
    float ry = fmaxf(fmaf(s_y, dn, by), 0.f);
    unsigned int packed = ((unsigned int)f2b(ry) << 16) | (unsigned int)f2b(rx);
    __builtin_nontemporal_store(packed, &hout[(size_t)node*64 + lane]);
}

// ---------------- MLP head ----------------

__global__ void head_kernel(const float* __restrict__ pooled,
                            const float* __restrict__ Wm1, const float* __restrict__ bm1,
                            const float* __restrict__ Wm2, const float* __restrict__ bm2,
                            float* __restrict__ out){
    __shared__ float p[128];
    __shared__ float tq[128];
    int g = blockIdx.x, j = threadIdx.x;
    p[j] = pooled[g*128 + j];
    __syncthreads();
    float a = bm1[j];
    for(int k = 0; k < 128; ++k) a = fmaf(p[k], Wm1[k*128 + j], a);
    tq[j] = fmaxf(a, 0.f);
    __syncthreads();
    if(j < 10){
        float o = bm2[j];
        for(int k = 0; k < 128; ++k) o = fmaf(tq[k], Wm2[k*10 + j], o);
        out[g*10 + j] = o;
    }
}

// ---------------- launch ----------------

extern "C" void kernel_launch(void* const* d_in, const int* in_sizes, int n_in,
                              void* d_out, int out_size, void* d_ws, size_t ws_size,
                              hipStream_t stream){
    const float* x    = (const float*)d_in[0];
    const int*   ei   = (const int*)  d_in[1];
    const int*   batch= (const int*)  d_in[2];
    const float* W0   = (const float*)d_in[3];
    const float* b0   = (const float*)d_in[4];
    const float* W1   = (const float*)d_in[5];
    const float* b1   = (const float*)d_in[6];
    const float* W2   = (const float*)d_in[7];
    const float* b2   = (const float*)d_in[8];
    const float* Wjk  = (const float*)d_in[9];
    const float* bjk  = (const float*)d_in[10];
    const float* Wm1  = (const float*)d_in[11];
    const float* bm1  = (const float*)d_in[12];
    const float* Wm2  = (const float*)d_in[13];
    const float* bm2  = (const float*)d_in[14];

    const int N = in_sizes[0] / 128;
    const int E = in_sizes[1] / 2;
    const int* src = ei;
    const int* dst = ei + E;

    const int nbuck = (N + (1<<BSHIFT) - 1) >> BSHIFT;            // 49 for N=100k
    const int cap   = E/nbuck + E/(nbuck*4) + 2048;               // mean + 25% + slack

    char* ws = (char*)d_ws;
    size_t off = 0;
    auto take = [&](size_t bytes)->char*{
        char* p = ws + off; off = (off + bytes + 255) & ~(size_t)255; return p;
    };
    unsigned short* Y    = (unsigned short*)take((size_t)N*128*2);    // bf16 row-major
    unsigned short* Habc = (unsigned short*)take((size_t)3*N*128*2);  // bf16 [3][N][128]
    float* dinv    = (float*)take((size_t)N*4);
    int*   deg     = (int*)  take((size_t)N*4);
    int*   cursor  = (int*)  take((size_t)N*4);
    int*   row_start=(int*)  take((size_t)(N+1)*4);
    int*   csr_src = (int*)  take((size_t)E*4 + 64);
    float* pooled  = (float*)take((size_t)512*128*4);
    int*   partials= (int*)  take((size_t)512*4);
    unsigned short* Whi = (unsigned short*)take((size_t)6*16384*2);
    int*   bcursor = (int*)  take((size_t)64*4);
    int*   stage   = (int*)  take((size_t)nbuck*cap*4);

    int nb = (N + 255)/256;
    int bgrid = 8 * ((nbuck + 7)/8) * CPB;

    prep_w_all     <<<384, 256, 0, stream>>>(W0, W1, W2, Wjk, Whi, pooled, bcursor);
    partition_edges<<<(E + 256*EPT - 1)/(256*EPT), 256, 0, stream>>>(src, dst, E, N, deg, bcursor, stage, cap);
    hist_b         <<<bgrid, 256, 0, stream>>>(stage, bcursor, cap, nbuck, deg);
    scan_part      <<<nb, 256, 0, stream>>>(deg, N, partials);
    scan_partials_k<<<1, 512, 0, stream>>>(partials, nb);
    scan_final     <<<nb, 256, 0, stream>>>(deg, N, partials, row_start, cursor, dinv);
    fill_b         <<<bgrid, 256, 0, stream>>>(stage, bcursor, cap, nbuck, cursor, csr_src);

    int gb = (N + 127)/128;
    int ab = (N + 3)/4;
    unsigned short* H0 = Habc;
    unsigned short* H1 = Habc + (size_t)N*128;
    unsigned short* H2 = Habc + (size_t)2*N*128;

    // layer 1 (f32 A converted in-register)
    gemm_f32A<<<gb, 512, 0, stream>>>(x,  Whi,           dinv, Y, N);
    aggregate<<<ab, 256, 0, stream>>>((const unsigned int*)Y, row_start, csr_src, dinv, b0, (unsigned int*)H0, N);
    // layer 2
    gemm_b16A<<<gb, 512, 0, stream>>>(H0, Whi + 1*16384, dinv, Y, N);
    aggregate<<<ab, 256, 0, stream>>>((const unsigned int*)Y, row_start, csr_src, dinv, b1, (unsigned int*)H1, N);
    // layer 3
    gemm_b16A<<<gb, 512, 0, stream>>>(H1, Whi + 2*16384, dinv, Y, N);
    aggregate<<<ab, 256, 0, stream>>>((const unsigned int*)Y, row_start, csr_src, dinv, b2, (unsigned int*)H2, N);
    // JK projection + fused pooling (K=384, bf16 W)
    gemm_jk_pool<<<gb, 512, 0, stream>>>(Habc, Whi, bjk, batch, pooled, N);

    head_kernel<<<512, 128, 0, stream>>>(pooled, Wm1, bm1, Wm2, bm2, (float*)d_out);
}

// Round 12
// 346.522 us; speedup vs baseline: 4.6755x; 1.2935x over previous
//
#include <hip/hip_runtime.h>

typedef __attribute__((ext_vector_type(8))) short bf16x8;
typedef __attribute__((ext_vector_type(4))) float f32x4;

#define BSHIFT 9                 // 512-node buckets -> 196 buckets at N=100k
#define BSZ (1<<BSHIFT)
#define EPT 8

__device__ inline unsigned short f2b(float x){
    union{float f; unsigned int u;} c; c.f = x;
    unsigned int r = c.u + 0x7fffu + ((c.u >> 16) & 1u);
    return (unsigned short)(r >> 16);
}
__device__ inline float b2f_lo(unsigned int u){
    union{unsigned int u; float f;} c; c.u = u << 16; return c.f;
}
__device__ inline float b2f_hi(unsigned int u){
    union{unsigned int u; float f;} c; c.u = u & 0xffff0000u; return c.f;
}

// ---------------- CSR build, stage 1: partition edges into dst-range buckets ----------------
// packed v = (src << BSHIFT) | (dst & (BSZ-1));  src < 2^17, so 17+9 = 26 bits: fits.

__global__ __launch_bounds__(256) void partition_edges(const int* __restrict__ src, const int* __restrict__ dst,
                                                       int E, int* __restrict__ bcursor,
                                                       int* __restrict__ stage, int cap){
    __shared__ int lcount[256];
    __shared__ int lbase[256];
    int t = threadIdx.x;
    lcount[t] = 0;
    __syncthreads();
    int e0 = blockIdx.x*256*EPT + t;
    int b[EPT], rank[EPT], v[EPT];
    #pragma unroll
    for(int i = 0; i < EPT; ++i){
        int e = e0 + i*256;
        bool ok = e < E;
        int d = ok ? dst[e] : 0;
        int s = ok ? src[e] : 0;
        b[i] = d >> BSHIFT;
        v[i] = (s << BSHIFT) | (d & (BSZ-1));
        rank[i] = ok ? atomicAdd(&lcount[b[i]], 1) : -1;
    }
    __syncthreads();
    {
        int c = lcount[t];
        lbase[t] = (c > 0) ? atomicAdd(&bcursor[t], c) : 0;
    }
    __syncthreads();
    #pragma unroll
    for(int i = 0; i < EPT; ++i){
        if(rank[i] >= 0){
            int pos = lbase[b[i]] + rank[i];
            if(pos < cap) stage[(size_t)b[i]*cap + pos] = v[i];
        }
    }
}

// ---------------- CSR build, stage 2: one block per bucket, all in LDS ----------------
// Replaces hist + 3-kernel scan + fill. Writes row_start, dinv, csr_src.

__global__ __launch_bounds__(1024) void bucket_build(const int* __restrict__ stage, const int* __restrict__ bcnt,
                                                     int cap, int nb, int n,
                                                     int* __restrict__ row_start, float* __restrict__ dinv,
                                                     int* __restrict__ csr_src){
    __shared__ int hist[BSZ];          // per-node degree, then cursor
    __shared__ int red[1024];
    int b = blockIdx.x;
    int t = threadIdx.x;

    // bucket base = exclusive prefix of stored counts over buckets [0, b)
    red[t] = (t < nb && t < b) ? min(bcnt[t], cap) : 0;
    __syncthreads();
    for(int s = 512; s > 0; s >>= 1){ if(t < s) red[t] += red[t+s]; __syncthreads(); }
    int bucket_base = red[0];
    __syncthreads();

    int cnt = min(bcnt[b], cap);
    const int* sp = stage + (size_t)b*cap;

    for(int i = t; i < BSZ; i += 1024) hist[i] = 0;
    __syncthreads();
    for(int i = t; i < cnt; i += 1024) atomicAdd(&hist[sp[i] & (BSZ-1)], 1);
    __syncthreads();

    // exclusive scan of hist[0..BSZ) (Hillis-Steele in red)
    int hv = (t < BSZ) ? hist[t] : 0;
    if(t < BSZ) red[t] = hv;
    __syncthreads();
    for(int s = 1; s < BSZ; s <<= 1){
        int add = (t < BSZ && t >= s) ? red[t-s] : 0;
        __syncthreads();
        if(t < BSZ) red[t] += add;
        __syncthreads();
    }
    if(t < BSZ){
        int node = (b << BSHIFT) + t;
        if(node < n){
            int start = bucket_base + red[t] - hv;    // exclusive
            row_start[node] = start;
            dinv[node] = rsqrtf((float)hv + 1.0f);
            hist[t] = start;                           // becomes cursor
            if(node == n-1) row_start[n] = bucket_base + red[t];
        }
    }
    __syncthreads();

    for(int i = t; i < cnt; i += 1024){
        int v = sp[i];
        int p = atomicAdd(&hist[v & (BSZ-1)], 1);
        csr_src[p] = v >> BSHIFT;
    }
}

// ---------------- weight prep: f32 -> transposed, XOR-swizzled bf16 ----------------
// Runs FIRST; spare threads zero pooled and bcursor.

__global__ void prep_w_all(const float* __restrict__ W0, const float* __restrict__ W1,
                           const float* __restrict__ W2, const float* __restrict__ Wjk,
                           unsigned short* __restrict__ hi,
                           float* __restrict__ pooled, int* __restrict__ bcursor){
    int m = blockIdx.x >> 6;                         // 0..5
    int i = (blockIdx.x & 63)*256 + threadIdx.x;     // 0..16383
    int tid = blockIdx.x*256 + threadIdx.x;
    if(tid < 512*128) pooled[tid] = 0.f;
    if(tid < 256) bcursor[tid] = 0;
    const float* W = (m==0) ? W0 : (m==1) ? W1 : (m==2) ? W2 : (Wjk + (m-3)*16384);
    int k = i >> 7, c = i & 127;                     // W is [k][c]
    hi[(size_t)m*16384 + c*128 + (k ^ ((c & 7) << 3))] = f2b(W[i]);
}

// ---------------- GEMM (layer 1): out_bf16 = (bf16(x_f32) @ W) * dinv_row ----------------

__global__ __launch_bounds__(512) void gemm_f32A(const float* __restrict__ in,
                                                 const unsigned short* __restrict__ Wt_hi,
                                                 const float* __restrict__ dinv,
                                                 unsigned short* __restrict__ out, int n){
    __shared__ __align__(16) unsigned short Bs[16384];
    int t = threadIdx.x;
    int lane = t & 63;
    int r0 = blockIdx.x*128 + (t >> 6)*16;
    int lr = lane & 15;
    int lk = (lane >> 4) * 8;

    {
        uint4* d = (uint4*)Bs;
        const uint4* sH = (const uint4*)Wt_hi;
        #pragma unroll
        for(int i = 0; i < 4; ++i) d[t + i*512] = sH[t + i*512];
    }
    __syncthreads();

    f32x4 acc[8];
    #pragma unroll
    for(int c = 0; c < 8; ++c) acc[c] = (f32x4){0.f, 0.f, 0.f, 0.f};

    int arow_i = r0 + lr; if(arow_i > n-1) arow_i = n-1;
    const float* arow = in + (size_t)arow_i*128;

    #pragma unroll
    for(int k0 = 0; k0 < 128; k0 += 32){
        f32x4 a0 = *(const f32x4*)(arow + k0 + lk);
        f32x4 a1 = *(const f32x4*)(arow + k0 + lk + 4);
        bf16x8 ahi;
        #pragma unroll
        for(int j = 0; j < 4; ++j){
            ahi[j]   = (short)f2b(a0[j]);
            ahi[j+4] = (short)f2b(a1[j]);
        }
        int kidx = (k0 + lk) ^ ((lr & 7) << 3);
        #pragma unroll
        for(int c = 0; c < 8; ++c){
            bf16x8 bhi = *(const bf16x8*)&Bs[(c*16 + lr)*128 + kidx];
            acc[c] = __builtin_amdgcn_mfma_f32_16x16x32_bf16(ahi, bhi, acc[c], 0, 0, 0);
        }
    }

    float dv[4];
    #pragma unroll
    for(int i = 0; i < 4; ++i){
        int cr = r0 + ((lane >> 4) << 2) + i; if(cr > n-1) cr = n-1;
        dv[i] = dinv[cr];
    }
    #pragma unroll
    for(int c = 0; c < 8; ++c){
        int ccol = c*16 + lr;
        #pragma unroll
        for(int i = 0; i < 4; ++i){
            int crow = r0 + ((lane >> 4) << 2) + i;
            if(crow < n) out[(size_t)crow*128 + ccol] = f2b(acc[c][i] * dv[i]);
        }
    }
}

// ---------------- GEMM (layers 2,3): bf16 A, bf16 W ----------------

__global__ __launch_bounds__(512) void gemm_b16A(const unsigned short* __restrict__ in,
                                                 const unsigned short* __restrict__ Wt_hi,
                                                 const float* __restrict__ dinv,
                                                 unsigned short* __restrict__ out, int n){
    __shared__ __align__(16) unsigned short Bs[16384];
    int t = threadIdx.x;
    int lane = t & 63;
    int r0 = blockIdx.x*128 + (t >> 6)*16;
    int lr = lane & 15;
    int lk = (lane >> 4) * 8;

    {
        uint4* d = (uint4*)Bs;
        const uint4* sH = (const uint4*)Wt_hi;
        #pragma unroll
        for(int i = 0; i < 4; ++i) d[t + i*512] = sH[t + i*512];
    }
    __syncthreads();

    f32x4 acc[8];
    #pragma unroll
    for(int c = 0; c < 8; ++c) acc[c] = (f32x4){0.f, 0.f, 0.f, 0.f};

    int arow_i = r0 + lr; if(arow_i > n-1) arow_i = n-1;
    const unsigned short* arow = in + (size_t)arow_i*128;

    #pragma unroll
    for(int k0 = 0; k0 < 128; k0 += 32){
        bf16x8 ahi = *(const bf16x8*)(arow + k0 + lk);
        int kidx = (k0 + lk) ^ ((lr & 7) << 3);
        #pragma unroll
        for(int c = 0; c < 8; ++c){
            bf16x8 bhi = *(const bf16x8*)&Bs[(c*16 + lr)*128 + kidx];
            acc[c] = __builtin_amdgcn_mfma_f32_16x16x32_bf16(ahi, bhi, acc[c], 0, 0, 0);
        }
    }

    float dv[4];
    #pragma unroll
    for(int i = 0; i < 4; ++i){
        int cr = r0 + ((lane >> 4) << 2) + i; if(cr > n-1) cr = n-1;
        dv[i] = dinv[cr];
    }
    #pragma unroll
    for(int c = 0; c < 8; ++c){
        int ccol = c*16 + lr;
        #pragma unroll
        for(int i = 0; i < 4; ++i){
            int crow = r0 + ((lane >> 4) << 2) + i;
            if(crow < n) out[(size_t)crow*128 + ccol] = f2b(acc[c][i] * dv[i]);
        }
    }
}

// ---------------- JK GEMM + fused pooling ----------------

__global__ __launch_bounds__(512) void gemm_jk_pool(const unsigned short* __restrict__ habc,
                                                    const unsigned short* __restrict__ Whi,
                                                    const float* __restrict__ bias,
                                                    const int* __restrict__ batch,
                                                    float* __restrict__ pooled, int n){
    __shared__ __align__(16) unsigned short Bs[16384];
    int t = threadIdx.x;
    int lane = t & 63;
    int r0 = blockIdx.x*128 + (t >> 6)*16;
    int lr = lane & 15;
    int lk = (lane >> 4) * 8;

    f32x4 acc[8];
    #pragma unroll
    for(int c = 0; c < 8; ++c) acc[c] = (f32x4){0.f, 0.f, 0.f, 0.f};

    int arow_i = r0 + lr; if(arow_i > n-1) arow_i = n-1;

    for(int kb3 = 0; kb3 < 3; ++kb3){
        __syncthreads();
        {
            uint4* d = (uint4*)Bs;
            const uint4* sH = (const uint4*)(Whi + (size_t)(3 + kb3)*16384);
            #pragma unroll
            for(int i = 0; i < 4; ++i) d[t + i*512] = sH[t + i*512];
        }
        __syncthreads();

        const unsigned short* arow = habc + (size_t)kb3*n*128 + (size_t)arow_i*128;
        #pragma unroll
        for(int k0 = 0; k0 < 128; k0 += 32){
            bf16x8 ahi = *(const bf16x8*)(arow + k0 + lk);
            int kidx = (k0 + lk) ^ ((lr & 7) << 3);
            #pragma unroll
            for(int c = 0; c < 8; ++c){
                bf16x8 bhi = *(const bf16x8*)&Bs[(c*16 + lr)*128 + kidx];
                acc[c] = __builtin_amdgcn_mfma_f32_16x16x32_bf16(ahi, bhi, acc[c], 0, 0, 0);
            }
        }
    }

    // fused pooling epilogue
    int rbase = r0 + ((lane >> 4) << 2);
    int g[4];
    #pragma unroll
    for(int i = 0; i < 4; ++i){
        int crow = rbase + i;
        g[i] = (crow < n) ? batch[crow] : -1;
    }
    int gf = __shfl(g[0], 0);
    bool uni = __all(g[0]==gf && g[1]==gf && g[2]==gf && g[3]==gf && gf >= 0);

    #pragma unroll
    for(int c = 0; c < 8; ++c){
        int ccol = c*16 + lr;
        float bcol = bias[ccol];
        if(uni){
            float s = (acc[c][0]+bcol) + (acc[c][1]+bcol) + (acc[c][2]+bcol) + (acc[c][3]+bcol);
            s += __shfl_xor(s, 16);
            s += __shfl_xor(s, 32);
            if(lane < 16) atomicAdd(&pooled[gf*128 + ccol], s);
        } else {
            #pragma unroll
            for(int i = 0; i < 4; ++i){
                if(g[i] >= 0) atomicAdd(&pooled[g[i]*128 + ccol], acc[c][i] + bcol);
            }
        }
    }
}

// ---------------- pull aggregation (bf16 in/out, f32 accumulate) ----------------

__global__ __launch_bounds__(256) void aggregate(const unsigned int* __restrict__ y, const int* __restrict__ row_start,
                                                 const int* __restrict__ csr_src, const float* __restrict__ dinv,
                                                 const float* __restrict__ bias, unsigned int* __restrict__ hout, int n){
    int wave = threadIdx.x >> 6;
    int lane = threadIdx.x & 63;
    int node = blockIdx.x*4 + wave;
    if(node >= n) return;
    int s0 = row_start[node];
    int s1 = row_start[node+1];

    unsigned int self = y[(size_t)node*64 + lane];
    float ax[8], ay[8];
    ax[0] = b2f_lo(self); ay[0] = b2f_hi(self);
    #pragma unroll
    for(int u = 1; u < 8; ++u){ ax[u] = 0.f; ay[u] = 0.f; }

    int j = s0;
    for(; j + 8 <= s1; j += 8){
        int idx[8];
        #pragma unroll
        for(int u = 0; u < 8; ++u) idx[u] = csr_src[j+u];
        #pragma unroll
        for(int u = 0; u < 8; ++u){
            unsigned int v = y[(size_t)idx[u]*64 + lane];
            ax[u] += b2f_lo(v); ay[u] += b2f_hi(v);
        }
    }
    int rem = s1 - j;
    int idx[7];
    #pragma unroll
    for(int u = 0; u < 7; ++u) idx[u] = (u < rem) ? csr_src[j+u] : node;
    #pragma unroll
    for(int u = 0; u < 7; ++u){
        unsigned int v = y[(size_t)idx[u]*64 + lane];
        if(u < rem){ ax[u] += b2f_lo(v); ay[u] += b2f_hi(v); }
    }

    float s_x = ((ax[0]+ax[1]) + (ax[2]+ax[3])) + ((ax[4]+ax[5]) + (ax[6]+ax[7]));
    float s_y = ((ay[0]+ay[1]) + (ay[2]+ay[3])) + ((ay[4]+ay[5]) + (ay[6]+ay[7]));
    float dn = dinv[node];
    float bx = bias[lane*2], by = bias[lane*2+1];
    float rx = fmaxf(fmaf(s_x, dn, bx), 0.f);
    float ry = fmaxf(fmaf(s_y, dn, by), 0.f);
    unsigned int packed = ((unsigned int)f2b(ry) << 16) | (unsigned int)f2b(rx);
    __builtin_nontemporal_store(packed, &hout[(size_t)node*64 + lane]);
}

// ---------------- MLP head ----------------

__global__ void head_kernel(const float* __restrict__ pooled,
                            const float* __restrict__ Wm1, const float* __restrict__ bm1,
                            const float* __restrict__ Wm2, const float* __restrict__ bm2,
                            float* __restrict__ out){
    __shared__ float p[128];
    __shared__ float tq[128];
    int g = blockIdx.x, j = threadIdx.x;
    p[j] = pooled[g*128 + j];
    __syncthreads();
    float a = bm1[j];
    for(int k = 0; k < 128; ++k) a = fmaf(p[k], Wm1[k*128 + j], a);
    tq[j] = fmaxf(a, 0.f);
    __syncthreads();
    if(j < 10){
        float o = bm2[j];
        for(int k = 0; k < 128; ++k) o = fmaf(tq[k], Wm2[k*10 + j], o);
        out[g*10 + j] = o;
    }
}

// ---------------- launch ----------------

extern "C" void kernel_launch(void* const* d_in, const int* in_sizes, int n_in,
                              void* d_out, int out_size, void* d_ws, size_t ws_size,
                              hipStream_t stream){
    const float* x    = (const float*)d_in[0];
    const int*   ei   = (const int*)  d_in[1];
    const int*   batch= (const int*)  d_in[2];
    const float* W0   = (const float*)d_in[3];
    const float* b0   = (const float*)d_in[4];
    const float* W1   = (const float*)d_in[5];
    const float* b1   = (const float*)d_in[6];
    const float* W2   = (const float*)d_in[7];
    const float* b2   = (const float*)d_in[8];
    const float* Wjk  = (const float*)d_in[9];
    const float* bjk  = (const float*)d_in[10];
    const float* Wm1  = (const float*)d_in[11];
    const float* bm1  = (const float*)d_in[12];
    const float* Wm2  = (const float*)d_in[13];
    const float* bm2  = (const float*)d_in[14];

    const int N = in_sizes[0] / 128;
    const int E = in_sizes[1] / 2;
    const int* src = ei;
    const int* dst = ei + E;

    const int nbuck = (N + BSZ - 1) >> BSHIFT;                    // 196 for N=100k (<=256)
    const int cap   = E/nbuck + E/(nbuck*2) + 2048;               // mean + 50% + slack

    char* ws = (char*)d_ws;
    size_t off = 0;
    auto take = [&](size_t bytes)->char*{
        char* p = ws + off; off = (off + bytes + 255) & ~(size_t)255; return p;
    };
    unsigned short* Y    = (unsigned short*)take((size_t)N*128*2);    // bf16 row-major
    unsigned short* Habc = (unsigned short*)take((size_t)3*N*128*2);  // bf16 [3][N][128]
    float* dinv    = (float*)take((size_t)N*4);
    int*   row_start=(int*)  take((size_t)(N+1)*4);
    int*   csr_src = (int*)  take((size_t)E*4 + 64);
    float* pooled  = (float*)take((size_t)512*128*4);
    unsigned short* Whi = (unsigned short*)take((size_t)6*16384*2);
    int*   bcursor = (int*)  take((size_t)256*4);
    int*   stage   = (int*)  take((size_t)nbuck*cap*4);

    prep_w_all     <<<384, 256, 0, stream>>>(W0, W1, W2, Wjk, Whi, pooled, bcursor);
    partition_edges<<<(E + 256*EPT - 1)/(256*EPT), 256, 0, stream>>>(src, dst, E, bcursor, stage, cap);
    bucket_build   <<<nbuck, 1024, 0, stream>>>(stage, bcursor, cap, nbuck, N, row_start, dinv, csr_src);

    int gb = (N + 127)/128;
    int ab = (N + 3)/4;
    unsigned short* H0 = Habc;
    unsigned short* H1 = Habc + (size_t)N*128;
    unsigned short* H2 = Habc + (size_t)2*N*128;

    // layer 1 (f32 A converted in-register)
    gemm_f32A<<<gb, 512, 0, stream>>>(x,  Whi,           dinv, Y, N);
    aggregate<<<ab, 256, 0, stream>>>((const unsigned int*)Y, row_start, csr_src, dinv, b0, (unsigned int*)H0, N);
    // layer 2
    gemm_b16A<<<gb, 512, 0, stream>>>(H0, Whi + 1*16384, dinv, Y, N);
    aggregate<<<ab, 256, 0, stream>>>((const unsigned int*)Y, row_start, csr_src, dinv, b1, (unsigned int*)H1, N);
    // layer 3
    gemm_b16A<<<gb, 512, 0, stream>>>(H1, Whi + 2*16384, dinv, Y, N);
    aggregate<<<ab, 256, 0, stream>>>((const unsigned int*)Y, row_start, csr_src, dinv, b2, (unsigned int*)H2, N);
    // JK projection + fused pooling (K=384, bf16 W)
    gemm_jk_pool<<<gb, 512, 0, stream>>>(Habc, Whi, bjk, batch, pooled, N);

    head_kernel<<<512, 128, 0, stream>>>(pooled, Wm1, bm1, Wm2, bm2, (float*)d_out);
}